// Round 7
// baseline (1236.506 us; speedup 1.0000x reference)
//
#include <hip/hip_runtime.h>

#define NCV 100000
#define NTV 300000
#define NPV 50000
#define DD 128
#define OUTC 10
#define EMV 300000
#define EIV 600000
#define NTOT (2 * NTV + NCV + NPV)      // 750000 concatenated count slots
#define TOTE (2 * (EMV + EIV))          // 1800000 pool entries

typedef unsigned short u16;
typedef unsigned int u32;
typedef __attribute__((ext_vector_type(8))) short short8;   // 8 bf16 (4 VGPRs)
typedef __attribute__((ext_vector_type(4))) float floatx4;  // MFMA accumulator

union U4S8 { uint4 u; short8 s; };

__device__ __forceinline__ u16 f2bf(float f) {
  u32 x = __float_as_uint(f);
  return (u16)((x + 0x7fffu + ((x >> 16) & 1u)) >> 16);
}
__device__ __forceinline__ u32 pack2(float a, float b) {
  return (u32)f2bf(a) | ((u32)f2bf(b) << 16);
}
__device__ __forceinline__ void unpack8(uint4 q, float* v) {
  v[0] = __uint_as_float(q.x << 16); v[1] = __uint_as_float(q.x & 0xffff0000u);
  v[2] = __uint_as_float(q.y << 16); v[3] = __uint_as_float(q.y & 0xffff0000u);
  v[4] = __uint_as_float(q.z << 16); v[5] = __uint_as_float(q.z & 0xffff0000u);
  v[6] = __uint_as_float(q.w << 16); v[7] = __uint_as_float(q.w & 0xffff0000u);
}

// ---------------- weight prep: WB[n][k] bf16 (B-operand layout), bias fp32 ----------------
__global__ __launch_bounds__(256) void prep_w2(
    const float* __restrict__ Wn0, const float* __restrict__ Wn2,
    const float* __restrict__ Wr0, const float* __restrict__ Wr2,
    const float* __restrict__ b0, const float* __restrict__ b2,
    u16* __restrict__ WB, float* __restrict__ bt) {
  int i = blockIdx.x * 256 + threadIdx.x;
  if (i >= 128 * 384) return;
  int nn = i / 384, k = i % 384;
  float v;
  if (k < 128) v = Wn0[k * 128 + nn];
  else if (k < 256) v = Wn2[(k - 128) * 128 + nn];
  else v = Wr0[(k - 256) * 128 + nn] + Wr2[(k - 256) * 128 + nn];
  WB[i] = f2bf(v);
  if (i < 128) bt[i] = b0[i] + b2[i];
}

__global__ __launch_bounds__(256) void prep_w1(
    const float* __restrict__ Wn, const float* __restrict__ Wr,
    const float* __restrict__ b, u16* __restrict__ WB, float* __restrict__ bt) {
  int i = blockIdx.x * 256 + threadIdx.x;
  if (i >= 128 * 256) return;
  int nn = i / 256, k = i % 256;
  float v = (k < 128) ? Wn[k * 128 + nn] : Wr[(k - 128) * 128 + nn];
  WB[i] = f2bf(v);
  if (i < 128) bt[i] = b[i];
}

// ---------------- CSR build ----------------
__global__ __launch_bounds__(256) void count_kernel(
    const int* __restrict__ idxs, int* __restrict__ cnt, int ne) {
  int e = blockIdx.x * 256 + threadIdx.x;
  if (e < ne) atomicAdd(&cnt[idxs[e]], 1);
}

__global__ __launch_bounds__(256) void scan1_kernel(
    const int* __restrict__ cnt, int* __restrict__ off,
    int* __restrict__ bsum, int n) {
  __shared__ int sd[256];
  int tid = threadIdx.x;
  int base = blockIdx.x * 1024 + tid * 4;
  int v0 = 0, v1 = 0, v2 = 0, v3 = 0;
  if (base + 0 < n) v0 = cnt[base + 0];
  if (base + 1 < n) v1 = cnt[base + 1];
  if (base + 2 < n) v2 = cnt[base + 2];
  if (base + 3 < n) v3 = cnt[base + 3];
  int tsum = v0 + v1 + v2 + v3;
  sd[tid] = tsum;
  __syncthreads();
  for (int o = 1; o < 256; o <<= 1) {
    int xv = 0;
    if (tid >= o) xv = sd[tid - o];
    __syncthreads();
    sd[tid] += xv;
    __syncthreads();
  }
  int ex = sd[tid] - tsum;
  if (base + 0 < n) off[base + 0] = ex;
  if (base + 1 < n) off[base + 1] = ex + v0;
  if (base + 2 < n) off[base + 2] = ex + v0 + v1;
  if (base + 3 < n) off[base + 3] = ex + v0 + v1 + v2;
  if (tid == 255) bsum[blockIdx.x] = sd[255];
}

__global__ __launch_bounds__(256) void scan2_kernel(int* __restrict__ bsum, int nb) {
  __shared__ int sd[256];
  int tid = threadIdx.x;
  int base = tid * 4;
  int v0 = 0, v1 = 0, v2 = 0, v3 = 0;
  if (base + 0 < nb) v0 = bsum[base + 0];
  if (base + 1 < nb) v1 = bsum[base + 1];
  if (base + 2 < nb) v2 = bsum[base + 2];
  if (base + 3 < nb) v3 = bsum[base + 3];
  int tsum = v0 + v1 + v2 + v3;
  sd[tid] = tsum;
  __syncthreads();
  for (int o = 1; o < 256; o <<= 1) {
    int xv = 0;
    if (tid >= o) xv = sd[tid - o];
    __syncthreads();
    sd[tid] += xv;
    __syncthreads();
  }
  int ex = sd[tid] - tsum;
  if (base + 0 < nb) bsum[base + 0] = ex;
  if (base + 1 < nb) bsum[base + 1] = ex + v0;
  if (base + 2 < nb) bsum[base + 2] = ex + v0 + v1;
  if (base + 3 < nb) bsum[base + 3] = ex + v0 + v1 + v2;
}

__global__ __launch_bounds__(256) void scan3_kernel(
    int* __restrict__ off, const int* __restrict__ bsum,
    int* __restrict__ cur, int n, int tote) {
  int i = blockIdx.x * 256 + threadIdx.x;
  if (i > n) return;
  int v = (i == n) ? tote : (off[i] + bsum[i >> 10]);
  off[i] = v;
  cur[i] = v;
}

__global__ __launch_bounds__(256) void fill_kernel(
    const int* __restrict__ dsti, const int* __restrict__ srci,
    int* __restrict__ cur, int* __restrict__ pool, int ne) {
  int e = blockIdx.x * 256 + threadIdx.x;
  if (e >= ne) return;
  int pos = atomicAdd(&cur[dsti[e]], 1);
  pool[pos] = srci[e];
}

// ================= layer-0: fused-embed SAGE =================
// mean(embed(x_s)) = xbar*Wemb + b  (0 if deg==0). Gathers 4B scalars only.
template <int NSEG>
__global__ __launch_bounds__(256) void sage_emb(
    const float* __restrict__ xo, const float* __restrict__ Wo, const float* __restrict__ bo,
    const float* __restrict__ x1, const float* __restrict__ W1, const float* __restrict__ bc1,
    const int* __restrict__ off1,
    const float* __restrict__ x2, const float* __restrict__ W2, const float* __restrict__ bc2,
    const int* __restrict__ off2,
    const int* __restrict__ pool,
    const u16* __restrict__ WB, const float* __restrict__ bt,
    u16* __restrict__ out, int n, float alpha) {
  constexpr int KD = (NSEG + 1) * 128;
  constexpr int ST = KD + 8;
  __shared__ u16 At[32 * ST];
  __shared__ float AccS[32][NSEG * 8];
  __shared__ int soff[NSEG][33];
  int tid = threadIdx.x;
  int row0 = blockIdx.x * 32;

  if (tid < 33) soff[0][tid] = off1[min(row0 + tid, n)];
  if (NSEG == 2 && tid >= 64 && tid < 97) soff[1][tid - 64] = off2[min(row0 + tid - 64, n)];
  {
    float* a = (float*)AccS;
    a[tid] = 0.f;
    if (NSEG == 2) a[tid + 256] = 0.f;
  }
  __syncthreads();

  int row = tid >> 3, chunk = tid & 7;
  int grow = row0 + row;
  bool rok = grow < n;

  // own embed -> At cols [NSEG*128 + chunk*16)
  {
    float xv = rok ? xo[grow * 8 + chunk] : 0.f;
    const float4* w4 = (const float4*)Wo + chunk * 4;
    const float4* b4 = (const float4*)bo + chunk * 4;
    u32 o[8];
    #pragma unroll
    for (int q = 0; q < 4; ++q) {
      float4 w = w4[q], b = b4[q];
      o[2 * q + 0] = pack2(xv * w.x + b.x, xv * w.y + b.y);
      o[2 * q + 1] = pack2(xv * w.z + b.z, xv * w.w + b.w);
    }
    uint4* d = (uint4*)&At[row * ST + NSEG * 128 + chunk * 16];
    d[0] = make_uint4(o[0], o[1], o[2], o[3]);
    d[1] = make_uint4(o[4], o[5], o[6], o[7]);
  }

  // edge-parallel scalar gather: slot=contiguous edge run, feat=x column
  int slot = tid >> 3, feat = tid & 7;
  #pragma unroll
  for (int sg = 0; sg < NSEG; ++sg) {
    const int* so = soff[sg];
    const float* xs = sg ? x2 : x1;
    int eA = so[0];
    int nE = so[32] - eA;
    if (nE > 0) {
      int per = (nE + 31) >> 5;
      int a = eA + min(slot * per, nE);
      int b = eA + min(slot * per + per, nE);
      if (a < b) {
        int lo = 0, hi = 32;
        while (hi - lo > 1) { int mid = (lo + hi) >> 1; if (so[mid] <= a) lo = mid; else hi = mid; }
        int r = lo;
        float accv = 0.f;
        bool any = false;
        for (int e = a; e < b; ++e) {
          while (so[r + 1] <= e) {
            if (any) { atomicAdd(&AccS[r][sg * 8 + feat], accv); accv = 0.f; any = false; }
            r++;
          }
          int s = pool[e];
          accv += xs[s * 8 + feat];
          any = true;
        }
        if (any) atomicAdd(&AccS[r][sg * 8 + feat], accv);
      }
    }
  }
  __syncthreads();

  // mean expansion -> At
  #pragma unroll
  for (int sg = 0; sg < NSEG; ++sg) {
    int deg = soff[sg][row + 1] - soff[sg][row];
    float g = (deg > 0) ? 1.f : 0.f;
    float xbar = AccS[row][sg * 8 + chunk] / fmaxf((float)deg, 1.f);
    const float4* w4 = (const float4*)(sg ? W2 : W1) + chunk * 4;
    const float4* b4 = (const float4*)(sg ? bc2 : bc1) + chunk * 4;
    u32 o[8];
    #pragma unroll
    for (int q = 0; q < 4; ++q) {
      float4 w = w4[q], b = b4[q];
      o[2 * q + 0] = pack2(xbar * w.x + g * b.x, xbar * w.y + g * b.y);
      o[2 * q + 1] = pack2(xbar * w.z + g * b.z, xbar * w.w + g * b.w);
    }
    uint4* d = (uint4*)&At[row * ST + sg * 128 + chunk * 16];
    d[0] = make_uint4(o[0], o[1], o[2], o[3]);
    d[1] = make_uint4(o[4], o[5], o[6], o[7]);
  }
  __syncthreads();

  // MFMA phase
  int w = tid >> 6, lane = tid & 63;
  int m16 = lane & 15, quad = lane >> 4;
  int rb = (w & 1) * 16;
  int cg = (w >> 1) * 64;
  floatx4 acc[4];
  #pragma unroll
  for (int t = 0; t < 4; ++t) acc[t] = (floatx4){0.f, 0.f, 0.f, 0.f};
  const u16* arow = &At[(rb + m16) * ST + quad * 8];
  const u16* brow = &WB[(size_t)(cg + m16) * KD + quad * 8];
  #pragma unroll 2
  for (int ks = 0; ks < KD / 32; ++ks) {
    U4S8 av; av.u = *(const uint4*)(arow + ks * 32);
    #pragma unroll
    for (int t = 0; t < 4; ++t) {
      U4S8 bv; bv.u = *(const uint4*)(brow + (size_t)t * 16 * KD + ks * 32);
      acc[t] = __builtin_amdgcn_mfma_f32_16x16x32_bf16(av.s, bv.s, acc[t], 0, 0, 0);
    }
  }
  #pragma unroll
  for (int t = 0; t < 4; ++t) {
    int col = cg + t * 16 + m16;
    float bb = bt[col];
    #pragma unroll
    for (int r = 0; r < 4; ++r) {
      int rr = row0 + rb + quad * 4 + r;
      if (rr < n) out[(size_t)rr * 128 + col] = f2bf(alpha * (acc[t][r] + bb));
    }
  }
}

// ================= layer-1: edge-parallel vector-gather SAGE (2 relations) =================
__global__ __launch_bounds__(256) void sage_gat(
    const u16* __restrict__ hown,
    const u16* __restrict__ hs1, const int* __restrict__ off1,
    const u16* __restrict__ hs2, const int* __restrict__ off2,
    const int* __restrict__ pool,
    const u16* __restrict__ WB, const float* __restrict__ bt,
    u16* __restrict__ out, int n, float alpha) {
  constexpr int KD = 384;
  constexpr int ST = KD + 8;          // 392 u16 per At row
  constexpr int STF = 260;            // fp32 accumulator row stride
  __shared__ float Acc[32 * STF];     // 33,280 B; At (25,088 B) aliases this
  __shared__ int soff[2][33];
  u16* At = (u16*)Acc;
  int tid = threadIdx.x;
  int row0 = blockIdx.x * 32;

  if (tid < 33) soff[0][tid] = off1[min(row0 + tid, n)];
  if (tid >= 64 && tid < 97) soff[1][tid - 64] = off2[min(row0 + tid - 64, n)];
  for (int i = tid; i < 32 * STF; i += 256) Acc[i] = 0.f;
  __syncthreads();

  int slot = tid >> 3, chunk = tid & 7;

  // edge-parallel vector gather, both segments
  #pragma unroll
  for (int sg = 0; sg < 2; ++sg) {
    const int* so = soff[sg];
    const u16* hs = sg ? hs2 : hs1;
    int eA = so[0];
    int nE = so[32] - eA;
    if (nE <= 0) continue;
    int per = (nE + 31) >> 5;
    int a = eA + min(slot * per, nE);
    int b = eA + min(slot * per + per, nE);
    if (a >= b) continue;
    int lo = 0, hi = 32;
    while (hi - lo > 1) { int mid = (lo + hi) >> 1; if (so[mid] <= a) lo = mid; else hi = mid; }
    int r = lo;
    float acc[16];
    #pragma unroll
    for (int i = 0; i < 16; ++i) acc[i] = 0.f;
    bool any = false;
    for (int e = a; e < b; ++e) {
      while (so[r + 1] <= e) {
        if (any) {
          float* base = &Acc[r * STF + sg * 128 + chunk * 16];
          #pragma unroll
          for (int i = 0; i < 16; ++i) { atomicAdd(base + i, acc[i]); acc[i] = 0.f; }
          any = false;
        }
        r++;
      }
      int s = pool[e];
      const uint4* p = (const uint4*)hs + (size_t)s * 16 + chunk * 2;
      uint4 q0 = p[0], q1 = p[1];
      float v[16];
      unpack8(q0, v); unpack8(q1, v + 8);
      #pragma unroll
      for (int i = 0; i < 16; ++i) acc[i] += v[i];
      any = true;
    }
    if (any) {
      float* base = &Acc[r * STF + sg * 128 + chunk * 16];
      #pragma unroll
      for (int i = 0; i < 16; ++i) atomicAdd(base + i, acc[i]);
    }
  }

  // own row: global load (issued before barrier, consumed after)
  int row = slot;
  int grow = row0 + row;
  bool rok = grow < n;
  uint4 own0 = make_uint4(0, 0, 0, 0), own1 = own0;
  if (rok) {
    const uint4* p = (const uint4*)hown + (size_t)grow * 16 + chunk * 2;
    own0 = p[0]; own1 = p[1];
  }
  __syncthreads();

  // read accumulators into registers
  int d0 = soff[0][row + 1] - soff[0][row];
  int d1 = soff[1][row + 1] - soff[1][row];
  float inv0 = 1.f / fmaxf((float)d0, 1.f);
  float inv1 = 1.f / fmaxf((float)d1, 1.f);
  float m0[16], m1[16];
  {
    const float* a0 = &Acc[row * STF + chunk * 16];
    const float* a1 = &Acc[row * STF + 128 + chunk * 16];
    #pragma unroll
    for (int i = 0; i < 16; ++i) { m0[i] = a0[i] * inv0; m1[i] = a1[i] * inv1; }
  }
  __syncthreads();  // all Acc reads done before aliased At writes

  {
    u32 o[8];
    #pragma unroll
    for (int q = 0; q < 8; ++q) o[q] = pack2(m0[2 * q], m0[2 * q + 1]);
    uint4* d = (uint4*)&At[row * ST + chunk * 16];
    d[0] = make_uint4(o[0], o[1], o[2], o[3]);
    d[1] = make_uint4(o[4], o[5], o[6], o[7]);
    #pragma unroll
    for (int q = 0; q < 8; ++q) o[q] = pack2(m1[2 * q], m1[2 * q + 1]);
    d = (uint4*)&At[row * ST + 128 + chunk * 16];
    d[0] = make_uint4(o[0], o[1], o[2], o[3]);
    d[1] = make_uint4(o[4], o[5], o[6], o[7]);
    d = (uint4*)&At[row * ST + 256 + chunk * 16];
    d[0] = own0; d[1] = own1;
  }
  __syncthreads();

  // MFMA phase
  int w = tid >> 6, lane = tid & 63;
  int m16 = lane & 15, quad = lane >> 4;
  int rb = (w & 1) * 16;
  int cg = (w >> 1) * 64;
  floatx4 acm[4];
  #pragma unroll
  for (int t = 0; t < 4; ++t) acm[t] = (floatx4){0.f, 0.f, 0.f, 0.f};
  const u16* arow = &At[(rb + m16) * ST + quad * 8];
  const u16* brow = &WB[(size_t)(cg + m16) * KD + quad * 8];
  #pragma unroll 2
  for (int ks = 0; ks < KD / 32; ++ks) {
    U4S8 av; av.u = *(const uint4*)(arow + ks * 32);
    #pragma unroll
    for (int t = 0; t < 4; ++t) {
      U4S8 bv; bv.u = *(const uint4*)(brow + (size_t)t * 16 * KD + ks * 32);
      acm[t] = __builtin_amdgcn_mfma_f32_16x16x32_bf16(av.s, bv.s, acm[t], 0, 0, 0);
    }
  }
  #pragma unroll
  for (int t = 0; t < 4; ++t) {
    int col = cg + t * 16 + m16;
    float bb = bt[col];
    #pragma unroll
    for (int r = 0; r < 4; ++r) {
      int rr = row0 + rb + quad * 4 + r;
      if (rr < n) out[(size_t)rr * 128 + col] = f2bf(alpha * (acm[t][r] + bb));
    }
  }
}

// ---------------- head: softmax(h @ W_out + b_out) -> fp32 out ----------------
__global__ __launch_bounds__(256) void out_softmax(
    const u16* __restrict__ h, const float* __restrict__ Wout,
    const float* __restrict__ bout, float* __restrict__ out, int n) {
  __shared__ float sw[DD * OUTC];
  __shared__ float sb[OUTC];
  int tid = threadIdx.x;
  for (int i = tid; i < DD * OUTC; i += 256) sw[i] = Wout[i];
  if (tid < OUTC) sb[tid] = bout[tid];
  __syncthreads();
  int row = blockIdx.x * 256 + tid;
  if (row >= n) return;
  float logit[OUTC];
  #pragma unroll
  for (int o = 0; o < OUTC; ++o) logit[o] = sb[o];
  const uint4* hp = (const uint4*)h + (size_t)row * 16;
  for (int k = 0; k < DD; k += 8) {
    float v[8];
    unpack8(hp[k >> 3], v);
    #pragma unroll
    for (int j = 0; j < 8; ++j) {
      #pragma unroll
      for (int o = 0; o < OUTC; ++o) logit[o] += v[j] * sw[(k + j) * OUTC + o];
    }
  }
  float m = logit[0];
  #pragma unroll
  for (int o = 1; o < OUTC; ++o) m = fmaxf(m, logit[o]);
  float s = 0.f;
  #pragma unroll
  for (int o = 0; o < OUTC; ++o) { logit[o] = __expf(logit[o] - m); s += logit[o]; }
  float invs = 1.0f / s;
  #pragma unroll
  for (int o = 0; o < OUTC; ++o) out[(size_t)row * OUTC + o] = logit[o] * invs;
}

extern "C" void kernel_launch(void* const* d_in, const int* in_sizes, int n_in,
                              void* d_out, int out_size, void* d_ws, size_t ws_size,
                              hipStream_t stream) {
  const float* x_c   = (const float*)d_in[0];
  const float* x_t   = (const float*)d_in[1];
  const float* x_p   = (const float*)d_in[2];
  const float* W_col = (const float*)d_in[3];
  const float* b_col = (const float*)d_in[4];
  const float* Wn    = (const float*)d_in[5];
  const float* Wr    = (const float*)d_in[6];
  const float* b_lin = (const float*)d_in[7];
  const float* W_out = (const float*)d_in[8];
  const float* b_out = (const float*)d_in[9];
  const int* e_m_src = (const int*)d_in[10];
  const int* e_m_dst = (const int*)d_in[11];
  const int* e_i_src = (const int*)d_in[12];
  const int* e_i_dst = (const int*)d_in[13];
  float* out = (float*)d_out;

  // ---- workspace carve-out (~132 MB) ----
  size_t cursor = 0;
  char* base = (char*)d_ws;
  auto alloc = [&](size_t bytes) {
    void* p = base + cursor;
    cursor += (bytes + 255) & ~(size_t)255;
    return p;
  };
  u16* h_t  = (u16*)alloc((size_t)NTV * DD * 2);
  u16* h_cB = (u16*)alloc((size_t)NCV * DD * 2);
  u16* h_pB = (u16*)alloc((size_t)NPV * DD * 2);
  int* pool = (int*)alloc((size_t)TOTE * 4);
  int* cnt  = (int*)alloc((size_t)NTOT * 4);
  int* off  = (int*)alloc((size_t)(NTOT + 1) * 4);
  int* cur  = (int*)alloc((size_t)(NTOT + 1) * 4);
  int* bsum = (int*)alloc(1024 * 4);
  u16* WB2a = (u16*)alloc((size_t)128 * 384 * 2);
  u16* WB2b = (u16*)alloc((size_t)128 * 384 * 2);
  u16* WB1c = (u16*)alloc((size_t)128 * 256 * 2);
  u16* WB1p = (u16*)alloc((size_t)128 * 256 * 2);
  float* bt2a = (float*)alloc(128 * 4);
  float* bt2b = (float*)alloc(128 * 4);
  float* bt1c = (float*)alloc(128 * 4);
  float* bt1p = (float*)alloc(128 * 4);

  // CSR seg bases: seg0 [0,NT): t<-c (makes); seg1 [NT,2NT): t<-p (in);
  // seg2 [2NT,2NT+NC): c<-t (makes); seg3: p<-t (in).
  const int S0 = 0, S1 = NTV, S2 = 2 * NTV, S3 = 2 * NTV + NCV;

  const float* Wn_l[2][4]; const float* Wr_l[2][4]; const float* b_l[2][4];
  for (int l = 0; l < 2; ++l)
    for (int r = 0; r < 4; ++r) {
      Wn_l[l][r] = Wn + (size_t)(l * 4 + r) * DD * DD;
      Wr_l[l][r] = Wr + (size_t)(l * 4 + r) * DD * DD;
      b_l[l][r]  = b_lin + (size_t)(l * 4 + r) * DD;
    }

  int gEM = (EMV + 255) / 256, gEI = (EIV + 255) / 256;

  // ---- weight prep ----
  prep_w2<<<192, 256, 0, stream>>>(Wn_l[0][0], Wn_l[0][2], Wr_l[0][0], Wr_l[0][2],
                                   b_l[0][0], b_l[0][2], WB2a, bt2a);
  prep_w2<<<192, 256, 0, stream>>>(Wn_l[1][0], Wn_l[1][2], Wr_l[1][0], Wr_l[1][2],
                                   b_l[1][0], b_l[1][2], WB2b, bt2b);
  prep_w1<<<128, 256, 0, stream>>>(Wn_l[0][1], Wr_l[0][1], b_l[0][1], WB1c, bt1c);
  prep_w1<<<128, 256, 0, stream>>>(Wn_l[0][3], Wr_l[0][3], b_l[0][3], WB1p, bt1p);

  // ---- CSR build ----
  hipMemsetAsync(cnt, 0, (size_t)NTOT * 4, stream);
  count_kernel<<<gEM, 256, 0, stream>>>(e_m_dst, cnt + S0, EMV);
  count_kernel<<<gEI, 256, 0, stream>>>(e_i_dst, cnt + S1, EIV);
  count_kernel<<<gEM, 256, 0, stream>>>(e_m_src, cnt + S2, EMV);
  count_kernel<<<gEI, 256, 0, stream>>>(e_i_src, cnt + S3, EIV);
  int nblk = (NTOT + 1023) / 1024;  // 733
  scan1_kernel<<<nblk, 256, 0, stream>>>(cnt, off, bsum, NTOT);
  scan2_kernel<<<1, 256, 0, stream>>>(bsum, nblk);
  scan3_kernel<<<(NTOT + 1 + 255) / 256, 256, 0, stream>>>(off, bsum, cur, NTOT, TOTE);
  fill_kernel<<<gEM, 256, 0, stream>>>(e_m_dst, e_m_src, cur + S0, pool, EMV);
  fill_kernel<<<gEI, 256, 0, stream>>>(e_i_dst, e_i_src, cur + S1, pool, EIV);
  fill_kernel<<<gEM, 256, 0, stream>>>(e_m_src, e_m_dst, cur + S2, pool, EMV);
  fill_kernel<<<gEI, 256, 0, stream>>>(e_i_src, e_i_dst, cur + S3, pool, EIV);

  int gT = NTV / 32, gC = NCV / 32, gP = (NPV + 31) / 32;
  const float* Wc0 = W_col + 0 * DD; const float* bc0 = b_col + 0 * DD;  // customer
  const float* Wc1 = W_col + 1 * DD; const float* bc1 = b_col + 1 * DD;  // transaction
  const float* Wc2 = W_col + 2 * DD; const float* bc2 = b_col + 2 * DD;  // product

  // ---- layer 0 (embed fused; no materialized embeds) ----
  sage_emb<1><<<gC, 256, 0, stream>>>(x_c, Wc0, bc0,
                                      x_t, Wc1, bc1, off + S2,
                                      nullptr, nullptr, nullptr, nullptr,
                                      pool, WB1c, bt1c, h_cB, NCV, 1.0f);
  sage_emb<1><<<gP, 256, 0, stream>>>(x_p, Wc2, bc2,
                                      x_t, Wc1, bc1, off + S3,
                                      nullptr, nullptr, nullptr, nullptr,
                                      pool, WB1p, bt1p, h_pB, NPV, 1.0f);
  sage_emb<2><<<gT, 256, 0, stream>>>(x_t, Wc1, bc1,
                                      x_c, Wc0, bc0, off + S0,
                                      x_p, Wc2, bc2, off + S1,
                                      pool, WB2a, bt2a, h_t, NTV, 0.5f);

  // ---- layer 1 (only h_t live downstream) ----
  sage_gat<<<gT, 256, 0, stream>>>(h_t, h_cB, off + S0, h_pB, off + S1, pool,
                                   WB2b, bt2b, h_t, NTV, 0.5f);

  // ---- head ----
  out_softmax<<<(NTV + 255) / 256, 256, 0, stream>>>(h_t, W_out, b_out, out, NTV);
}

// Round 8
// 1017.211 us; speedup vs baseline: 1.2156x; 1.2156x over previous
//
#include <hip/hip_runtime.h>

#define NCV 100000
#define NTV 300000
#define NPV 50000
#define DD 128
#define OUTC 10
#define EMV 300000
#define EIV 600000
#define NTOT (2 * NTV + NCV + NPV)      // 750000 concatenated count slots
#define TOTE (2 * (EMV + EIV))          // 1800000 pool entries

typedef unsigned short u16;
typedef unsigned int u32;
typedef __attribute__((ext_vector_type(8))) short short8;   // 8 bf16 (4 VGPRs)
typedef __attribute__((ext_vector_type(4))) float floatx4;  // MFMA accumulator

union U4S8 { uint4 u; short8 s; };

__device__ __forceinline__ u16 f2bf(float f) {
  u32 x = __float_as_uint(f);
  return (u16)((x + 0x7fffu + ((x >> 16) & 1u)) >> 16);
}
__device__ __forceinline__ u32 pack2(float a, float b) {
  return (u32)f2bf(a) | ((u32)f2bf(b) << 16);
}
__device__ __forceinline__ void unpack8(uint4 q, float* v) {
  v[0] = __uint_as_float(q.x << 16); v[1] = __uint_as_float(q.x & 0xffff0000u);
  v[2] = __uint_as_float(q.y << 16); v[3] = __uint_as_float(q.y & 0xffff0000u);
  v[4] = __uint_as_float(q.z << 16); v[5] = __uint_as_float(q.z & 0xffff0000u);
  v[6] = __uint_as_float(q.w << 16); v[7] = __uint_as_float(q.w & 0xffff0000u);
}

// ---------------- embed: h[n, f*16+d] = x[n,f]*W[f,d] + b[f,d]  (fp32 in, bf16 out) ----------------
__global__ __launch_bounds__(256) void embed_kernel(
    const float* __restrict__ x, const float* __restrict__ Wc,
    const float* __restrict__ bc, u16* __restrict__ h, int n) {
  int idx = blockIdx.x * 256 + threadIdx.x;
  if (idx >= n * 8) return;
  int node = idx >> 3, f = idx & 7;
  float xv = x[idx];
  const float4* w4 = (const float4*)Wc + f * 4;
  const float4* b4 = (const float4*)bc + f * 4;
  float r[16];
  #pragma unroll
  for (int q = 0; q < 4; ++q) {
    float4 w = w4[q], b = b4[q];
    r[q * 4 + 0] = xv * w.x + b.x;
    r[q * 4 + 1] = xv * w.y + b.y;
    r[q * 4 + 2] = xv * w.z + b.z;
    r[q * 4 + 3] = xv * w.w + b.w;
  }
  uint4 o0, o1;
  o0.x = pack2(r[0], r[1]);   o0.y = pack2(r[2], r[3]);
  o0.z = pack2(r[4], r[5]);   o0.w = pack2(r[6], r[7]);
  o1.x = pack2(r[8], r[9]);   o1.y = pack2(r[10], r[11]);
  o1.z = pack2(r[12], r[13]); o1.w = pack2(r[14], r[15]);
  uint4* hp = (uint4*)h + (size_t)node * 16 + f * 2;
  hp[0] = o0; hp[1] = o1;
}

// ---------------- weight prep: WB[n][k] bf16 (B-operand layout), bias fp32 ----------------
__global__ __launch_bounds__(256) void prep_w2(
    const float* __restrict__ Wn0, const float* __restrict__ Wn2,
    const float* __restrict__ Wr0, const float* __restrict__ Wr2,
    const float* __restrict__ b0, const float* __restrict__ b2,
    u16* __restrict__ WB, float* __restrict__ bt) {
  int i = blockIdx.x * 256 + threadIdx.x;
  if (i >= 128 * 384) return;
  int nn = i / 384, k = i % 384;
  float v;
  if (k < 128) v = Wn0[k * 128 + nn];
  else if (k < 256) v = Wn2[(k - 128) * 128 + nn];
  else v = Wr0[(k - 256) * 128 + nn] + Wr2[(k - 256) * 128 + nn];
  WB[i] = f2bf(v);
  if (i < 128) bt[i] = b0[i] + b2[i];
}

__global__ __launch_bounds__(256) void prep_w1(
    const float* __restrict__ Wn, const float* __restrict__ Wr,
    const float* __restrict__ b, u16* __restrict__ WB, float* __restrict__ bt) {
  int i = blockIdx.x * 256 + threadIdx.x;
  if (i >= 128 * 256) return;
  int nn = i / 256, k = i % 256;
  float v = (k < 128) ? Wn[k * 128 + nn] : Wr[(k - 128) * 128 + nn];
  WB[i] = f2bf(v);
  if (i < 128) bt[i] = b[i];
}

// ---------------- CSR build ----------------
__global__ __launch_bounds__(256) void count_kernel(
    const int* __restrict__ idxs, int* __restrict__ cnt, int ne) {
  int e = blockIdx.x * 256 + threadIdx.x;
  if (e < ne) atomicAdd(&cnt[idxs[e]], 1);
}

__global__ __launch_bounds__(256) void scan1_kernel(
    const int* __restrict__ cnt, int* __restrict__ off,
    int* __restrict__ bsum, int n) {
  __shared__ int sd[256];
  int tid = threadIdx.x;
  int base = blockIdx.x * 1024 + tid * 4;
  int v0 = 0, v1 = 0, v2 = 0, v3 = 0;
  if (base + 0 < n) v0 = cnt[base + 0];
  if (base + 1 < n) v1 = cnt[base + 1];
  if (base + 2 < n) v2 = cnt[base + 2];
  if (base + 3 < n) v3 = cnt[base + 3];
  int tsum = v0 + v1 + v2 + v3;
  sd[tid] = tsum;
  __syncthreads();
  for (int o = 1; o < 256; o <<= 1) {
    int xv = 0;
    if (tid >= o) xv = sd[tid - o];
    __syncthreads();
    sd[tid] += xv;
    __syncthreads();
  }
  int ex = sd[tid] - tsum;
  if (base + 0 < n) off[base + 0] = ex;
  if (base + 1 < n) off[base + 1] = ex + v0;
  if (base + 2 < n) off[base + 2] = ex + v0 + v1;
  if (base + 3 < n) off[base + 3] = ex + v0 + v1 + v2;
  if (tid == 255) bsum[blockIdx.x] = sd[255];
}

__global__ __launch_bounds__(256) void scan2_kernel(int* __restrict__ bsum, int nb) {
  __shared__ int sd[256];
  int tid = threadIdx.x;
  int base = tid * 4;
  int v0 = 0, v1 = 0, v2 = 0, v3 = 0;
  if (base + 0 < nb) v0 = bsum[base + 0];
  if (base + 1 < nb) v1 = bsum[base + 1];
  if (base + 2 < nb) v2 = bsum[base + 2];
  if (base + 3 < nb) v3 = bsum[base + 3];
  int tsum = v0 + v1 + v2 + v3;
  sd[tid] = tsum;
  __syncthreads();
  for (int o = 1; o < 256; o <<= 1) {
    int xv = 0;
    if (tid >= o) xv = sd[tid - o];
    __syncthreads();
    sd[tid] += xv;
    __syncthreads();
  }
  int ex = sd[tid] - tsum;
  if (base + 0 < nb) bsum[base + 0] = ex;
  if (base + 1 < nb) bsum[base + 1] = ex + v0;
  if (base + 2 < nb) bsum[base + 2] = ex + v0 + v1;
  if (base + 3 < nb) bsum[base + 3] = ex + v0 + v1 + v2;
}

__global__ __launch_bounds__(256) void scan3_kernel(
    int* __restrict__ off, const int* __restrict__ bsum,
    int* __restrict__ cur, int n, int tote) {
  int i = blockIdx.x * 256 + threadIdx.x;
  if (i > n) return;
  int v = (i == n) ? tote : (off[i] + bsum[i >> 10]);
  off[i] = v;
  cur[i] = v;
}

__global__ __launch_bounds__(256) void fill_kernel(
    const int* __restrict__ dsti, const int* __restrict__ srci,
    int* __restrict__ cur, int* __restrict__ pool, int ne) {
  int e = blockIdx.x * 256 + threadIdx.x;
  if (e >= ne) return;
  int pos = atomicAdd(&cur[dsti[e]], 1);
  pool[pos] = srci[e];
}

// ---------------- fused SAGE via MFMA, batched gather ----------------
// out[32 x 128] = A[32 x KD] @ WB (stored WB[n][k]) ; KD=(NSEG+1)*128
// A = [mean_1 | (mean_2) | own] staged in LDS row-major bf16, stride KD+8.
// Gather batches 4 edges: 4 independent pool loads, then 8 independent row
// loads issued before any accumulation -> 4x memory-level parallelism vs
// the serial per-edge chain (round-6 bottleneck).
template <int NSEG>
__global__ __launch_bounds__(256) void sage_mfma(
    const u16* __restrict__ hown,
    const u16* __restrict__ hs1, const int* __restrict__ off1,
    const u16* __restrict__ hs2, const int* __restrict__ off2,
    const int* __restrict__ pool,
    const u16* __restrict__ WB, const float* __restrict__ bt,
    u16* __restrict__ out, int n, float alpha) {
  constexpr int KD = (NSEG + 1) * 128;
  constexpr int ST = KD + 8;  // u16 units
  __shared__ u16 At[32 * ST];
  int tid = threadIdx.x;
  int row0 = blockIdx.x * 32;
  int row = tid >> 3, chunk = tid & 7;  // 8 threads/row, 32B chunks
  int grow = row0 + row;
  bool rok = grow < n;

  // own segment: raw 32B bf16 copy
  {
    uint4 a0 = make_uint4(0, 0, 0, 0), a1 = a0;
    if (rok) {
      const uint4* p = (const uint4*)hown + (size_t)grow * 16 + chunk * 2;
      a0 = p[0]; a1 = p[1];
    }
    uint4* d = (uint4*)&At[row * ST + NSEG * 128 + chunk * 16];
    d[0] = a0; d[1] = a1;
  }
  // mean segments: batched gather (4 edges in flight)
  const u16* hsrc[2] = {hs1, hs2};
  const int* offs[2] = {off1, off2};
  #pragma unroll
  for (int sgi = 0; sgi < NSEG; ++sgi) {
    float a[16];
    #pragma unroll
    for (int i = 0; i < 16; ++i) a[i] = 0.f;
    int deg = 0, j0 = 0;
    if (rok) { j0 = offs[sgi][grow]; deg = offs[sgi][grow + 1] - j0; }
    const uint4* hb = (const uint4*)hsrc[sgi];
    for (int jb = 0; jb < deg; jb += 4) {
      int idx[4];
      #pragma unroll
      for (int t = 0; t < 4; ++t) idx[t] = pool[j0 + min(jb + t, deg - 1)];
      uint4 q0[4], q1[4];
      #pragma unroll
      for (int t = 0; t < 4; ++t) {
        const uint4* p = hb + (size_t)idx[t] * 16 + chunk * 2;
        q0[t] = p[0]; q1[t] = p[1];
      }
      #pragma unroll
      for (int t = 0; t < 4; ++t) {
        if (jb + t < deg) {
          float v[16];
          unpack8(q0[t], v); unpack8(q1[t], v + 8);
          #pragma unroll
          for (int i = 0; i < 16; ++i) a[i] += v[i];
        }
      }
    }
    float inv = 1.f / fmaxf((float)deg, 1.f);
    u32 o[8];
    #pragma unroll
    for (int qq = 0; qq < 8; ++qq) o[qq] = pack2(a[2 * qq] * inv, a[2 * qq + 1] * inv);
    uint4* d = (uint4*)&At[row * ST + sgi * 128 + chunk * 16];
    d[0] = make_uint4(o[0], o[1], o[2], o[3]);
    d[1] = make_uint4(o[4], o[5], o[6], o[7]);
  }
  __syncthreads();

  // MFMA: wave w -> rowtile (w&1), col group 64*(w>>1), 4 coltiles of 16
  int w = tid >> 6, lane = tid & 63;
  int m16 = lane & 15, quad = lane >> 4;
  int rb = (w & 1) * 16;
  int cg = (w >> 1) * 64;
  floatx4 acc[4];
  #pragma unroll
  for (int t = 0; t < 4; ++t) acc[t] = (floatx4){0.f, 0.f, 0.f, 0.f};
  const u16* arow = &At[(rb + m16) * ST + quad * 8];
  const u16* brow = &WB[(size_t)(cg + m16) * KD + quad * 8];
  #pragma unroll 2
  for (int ks = 0; ks < KD / 32; ++ks) {
    U4S8 av; av.u = *(const uint4*)(arow + ks * 32);
    #pragma unroll
    for (int t = 0; t < 4; ++t) {
      U4S8 bv; bv.u = *(const uint4*)(brow + (size_t)t * 16 * KD + ks * 32);
      acc[t] = __builtin_amdgcn_mfma_f32_16x16x32_bf16(av.s, bv.s, acc[t], 0, 0, 0);
    }
  }
  // epilogue: D col = lane&15, row = quad*4 + reg
  #pragma unroll
  for (int t = 0; t < 4; ++t) {
    int col = cg + t * 16 + m16;
    float bb = bt[col];
    #pragma unroll
    for (int r = 0; r < 4; ++r) {
      int rr = row0 + rb + quad * 4 + r;
      if (rr < n) out[(size_t)rr * 128 + col] = f2bf(alpha * (acc[t][r] + bb));
    }
  }
}

// ---------------- head: softmax(h @ W_out + b_out) -> fp32 out ----------------
__global__ __launch_bounds__(256) void out_softmax(
    const u16* __restrict__ h, const float* __restrict__ Wout,
    const float* __restrict__ bout, float* __restrict__ out, int n) {
  __shared__ float sw[DD * OUTC];
  __shared__ float sb[OUTC];
  int tid = threadIdx.x;
  for (int i = tid; i < DD * OUTC; i += 256) sw[i] = Wout[i];
  if (tid < OUTC) sb[tid] = bout[tid];
  __syncthreads();
  int row = blockIdx.x * 256 + tid;
  if (row >= n) return;
  float logit[OUTC];
  #pragma unroll
  for (int o = 0; o < OUTC; ++o) logit[o] = sb[o];
  const uint4* hp = (const uint4*)h + (size_t)row * 16;
  for (int k = 0; k < DD; k += 8) {
    float v[8];
    unpack8(hp[k >> 3], v);
    #pragma unroll
    for (int j = 0; j < 8; ++j) {
      #pragma unroll
      for (int o = 0; o < OUTC; ++o) logit[o] += v[j] * sw[(k + j) * OUTC + o];
    }
  }
  float m = logit[0];
  #pragma unroll
  for (int o = 1; o < OUTC; ++o) m = fmaxf(m, logit[o]);
  float s = 0.f;
  #pragma unroll
  for (int o = 0; o < OUTC; ++o) { logit[o] = __expf(logit[o] - m); s += logit[o]; }
  float invs = 1.0f / s;
  #pragma unroll
  for (int o = 0; o < OUTC; ++o) out[(size_t)row * OUTC + o] = logit[o] * invs;
}

extern "C" void kernel_launch(void* const* d_in, const int* in_sizes, int n_in,
                              void* d_out, int out_size, void* d_ws, size_t ws_size,
                              hipStream_t stream) {
  const float* x_c   = (const float*)d_in[0];
  const float* x_t   = (const float*)d_in[1];
  const float* x_p   = (const float*)d_in[2];
  const float* W_col = (const float*)d_in[3];
  const float* b_col = (const float*)d_in[4];
  const float* Wn    = (const float*)d_in[5];
  const float* Wr    = (const float*)d_in[6];
  const float* b_lin = (const float*)d_in[7];
  const float* W_out = (const float*)d_in[8];
  const float* b_out = (const float*)d_in[9];
  const int* e_m_src = (const int*)d_in[10];
  const int* e_m_dst = (const int*)d_in[11];
  const int* e_i_src = (const int*)d_in[12];
  const int* e_i_dst = (const int*)d_in[13];
  float* out = (float*)d_out;

  // ---- workspace carve-out (~171 MB; round-5/6 proven footprint) ----
  size_t cursor = 0;
  char* base = (char*)d_ws;
  auto alloc = [&](size_t bytes) {
    void* p = base + cursor;
    cursor += (bytes + 255) & ~(size_t)255;
    return p;
  };
  u16* h_t  = (u16*)alloc((size_t)NTV * DD * 2);
  u16* h_cA = (u16*)alloc((size_t)NCV * DD * 2);
  u16* h_cB = (u16*)alloc((size_t)NCV * DD * 2);
  u16* h_pA = (u16*)alloc((size_t)NPV * DD * 2);
  u16* h_pB = (u16*)alloc((size_t)NPV * DD * 2);
  int* pool = (int*)alloc((size_t)TOTE * 4);
  int* cnt  = (int*)alloc((size_t)NTOT * 4);
  int* off  = (int*)alloc((size_t)(NTOT + 1) * 4);
  int* cur  = (int*)alloc((size_t)(NTOT + 1) * 4);
  int* bsum = (int*)alloc(1024 * 4);
  u16* WB2a = (u16*)alloc((size_t)128 * 384 * 2);
  u16* WB2b = (u16*)alloc((size_t)128 * 384 * 2);
  u16* WB1c = (u16*)alloc((size_t)128 * 256 * 2);
  u16* WB1p = (u16*)alloc((size_t)128 * 256 * 2);
  float* bt2a = (float*)alloc(128 * 4);
  float* bt2b = (float*)alloc(128 * 4);
  float* bt1c = (float*)alloc(128 * 4);
  float* bt1p = (float*)alloc(128 * 4);

  // CSR seg bases: seg0 [0,NT): t<-c (makes); seg1 [NT,2NT): t<-p (in);
  // seg2 [2NT,2NT+NC): c<-t (makes); seg3: p<-t (in).
  const int S0 = 0, S1 = NTV, S2 = 2 * NTV, S3 = 2 * NTV + NCV;

  const float* Wn_l[2][4]; const float* Wr_l[2][4]; const float* b_l[2][4];
  for (int l = 0; l < 2; ++l)
    for (int r = 0; r < 4; ++r) {
      Wn_l[l][r] = Wn + (size_t)(l * 4 + r) * DD * DD;
      Wr_l[l][r] = Wr + (size_t)(l * 4 + r) * DD * DD;
      b_l[l][r]  = b_lin + (size_t)(l * 4 + r) * DD;
    }

  int gEM = (EMV + 255) / 256, gEI = (EIV + 255) / 256;

  // ---- weight prep ----
  prep_w2<<<192, 256, 0, stream>>>(Wn_l[0][0], Wn_l[0][2], Wr_l[0][0], Wr_l[0][2],
                                   b_l[0][0], b_l[0][2], WB2a, bt2a);
  prep_w2<<<192, 256, 0, stream>>>(Wn_l[1][0], Wn_l[1][2], Wr_l[1][0], Wr_l[1][2],
                                   b_l[1][0], b_l[1][2], WB2b, bt2b);
  prep_w1<<<128, 256, 0, stream>>>(Wn_l[0][1], Wr_l[0][1], b_l[0][1], WB1c, bt1c);
  prep_w1<<<128, 256, 0, stream>>>(Wn_l[0][3], Wr_l[0][3], b_l[0][3], WB1p, bt1p);

  // ---- CSR build ----
  hipMemsetAsync(cnt, 0, (size_t)NTOT * 4, stream);
  count_kernel<<<gEM, 256, 0, stream>>>(e_m_dst, cnt + S0, EMV);
  count_kernel<<<gEI, 256, 0, stream>>>(e_i_dst, cnt + S1, EIV);
  count_kernel<<<gEM, 256, 0, stream>>>(e_m_src, cnt + S2, EMV);
  count_kernel<<<gEI, 256, 0, stream>>>(e_i_src, cnt + S3, EIV);
  int nblk = (NTOT + 1023) / 1024;  // 733
  scan1_kernel<<<nblk, 256, 0, stream>>>(cnt, off, bsum, NTOT);
  scan2_kernel<<<1, 256, 0, stream>>>(bsum, nblk);
  scan3_kernel<<<(NTOT + 1 + 255) / 256, 256, 0, stream>>>(off, bsum, cur, NTOT, TOTE);
  fill_kernel<<<gEM, 256, 0, stream>>>(e_m_dst, e_m_src, cur + S0, pool, EMV);
  fill_kernel<<<gEI, 256, 0, stream>>>(e_i_dst, e_i_src, cur + S1, pool, EIV);
  fill_kernel<<<gEM, 256, 0, stream>>>(e_m_src, e_m_dst, cur + S2, pool, EMV);
  fill_kernel<<<gEI, 256, 0, stream>>>(e_i_src, e_i_dst, cur + S3, pool, EIV);

  // ---- embeds ----
  embed_kernel<<<(NCV * 8 + 255) / 256, 256, 0, stream>>>(
      x_c, W_col + 0 * DD, b_col + 0 * DD, h_cA, NCV);
  embed_kernel<<<(NTV * 8 + 255) / 256, 256, 0, stream>>>(
      x_t, W_col + 1 * DD, b_col + 1 * DD, h_t, NTV);
  embed_kernel<<<(NPV * 8 + 255) / 256, 256, 0, stream>>>(
      x_p, W_col + 2 * DD, b_col + 2 * DD, h_pA, NPV);

  int gT = NTV / 32, gC = NCV / 32, gP = (NPV + 31) / 32;

  // ---- layer 0 ----
  sage_mfma<1><<<gC, 256, 0, stream>>>(h_cA, h_t, off + S2, nullptr, nullptr, pool,
                                       WB1c, bt1c, h_cB, NCV, 1.0f);
  sage_mfma<1><<<gP, 256, 0, stream>>>(h_pA, h_t, off + S3, nullptr, nullptr, pool,
                                       WB1p, bt1p, h_pB, NPV, 1.0f);
  sage_mfma<2><<<gT, 256, 0, stream>>>(h_t, h_cA, off + S0, h_pA, off + S1, pool,
                                       WB2a, bt2a, h_t, NTV, 0.5f);
  // ---- layer 1 (only h_t live downstream) ----
  sage_mfma<2><<<gT, 256, 0, stream>>>(h_t, h_cB, off + S0, h_pB, off + S1, pool,
                                       WB2b, bt2b, h_t, NTV, 0.5f);

  // ---- head ----
  out_softmax<<<(NTV + 255) / 256, 256, 0, stream>>>(h_t, W_out, b_out, out, NTV);
}

// Round 9
// 963.970 us; speedup vs baseline: 1.2827x; 1.0552x over previous
//
#include <hip/hip_runtime.h>

#define NCV 100000
#define NTV 300000
#define NPV 50000
#define DD 128
#define OUTC 10
#define EMV 300000
#define EIV 600000
#define NTOT (2 * NTV + NCV + NPV)      // 750000 concatenated count slots
#define TOTE (2 * (EMV + EIV))          // 1800000 pool entries

typedef unsigned short u16;
typedef unsigned int u32;
typedef __attribute__((ext_vector_type(8))) short short8;   // 8 bf16 (4 VGPRs)
typedef __attribute__((ext_vector_type(4))) float floatx4;  // MFMA accumulator

union U4S8 { uint4 u; short8 s; };

__device__ __forceinline__ u16 f2bf(float f) {
  u32 x = __float_as_uint(f);
  return (u16)((x + 0x7fffu + ((x >> 16) & 1u)) >> 16);
}
__device__ __forceinline__ u32 pack2(float a, float b) {
  return (u32)f2bf(a) | ((u32)f2bf(b) << 16);
}
__device__ __forceinline__ void unpack8(uint4 q, float* v) {
  v[0] = __uint_as_float(q.x << 16); v[1] = __uint_as_float(q.x & 0xffff0000u);
  v[2] = __uint_as_float(q.y << 16); v[3] = __uint_as_float(q.y & 0xffff0000u);
  v[4] = __uint_as_float(q.z << 16); v[5] = __uint_as_float(q.z & 0xffff0000u);
  v[6] = __uint_as_float(q.w << 16); v[7] = __uint_as_float(q.w & 0xffff0000u);
}

// ---------------- weight prep: WB[n][k] bf16 (B-operand layout), bias fp32 ----------------
__global__ __launch_bounds__(256) void prep_w2(
    const float* __restrict__ Wn0, const float* __restrict__ Wn2,
    const float* __restrict__ Wr0, const float* __restrict__ Wr2,
    const float* __restrict__ b0, const float* __restrict__ b2,
    u16* __restrict__ WB, float* __restrict__ bt) {
  int i = blockIdx.x * 256 + threadIdx.x;
  if (i >= 128 * 384) return;
  int nn = i / 384, k = i % 384;
  float v;
  if (k < 128) v = Wn0[k * 128 + nn];
  else if (k < 256) v = Wn2[(k - 128) * 128 + nn];
  else v = Wr0[(k - 256) * 128 + nn] + Wr2[(k - 256) * 128 + nn];
  WB[i] = f2bf(v);
  if (i < 128) bt[i] = b0[i] + b2[i];
}

__global__ __launch_bounds__(256) void prep_w1(
    const float* __restrict__ Wn, const float* __restrict__ Wr,
    const float* __restrict__ b, u16* __restrict__ WB, float* __restrict__ bt) {
  int i = blockIdx.x * 256 + threadIdx.x;
  if (i >= 128 * 256) return;
  int nn = i / 256, k = i % 256;
  float v = (k < 128) ? Wn[k * 128 + nn] : Wr[(k - 128) * 128 + nn];
  WB[i] = f2bf(v);
  if (i < 128) bt[i] = b[i];
}

// ---------------- CSR build ----------------
__global__ __launch_bounds__(256) void count_kernel(
    const int* __restrict__ idxs, int* __restrict__ cnt, int ne) {
  int e = blockIdx.x * 256 + threadIdx.x;
  if (e < ne) atomicAdd(&cnt[idxs[e]], 1);
}

__global__ __launch_bounds__(256) void scan1_kernel(
    const int* __restrict__ cnt, int* __restrict__ off,
    int* __restrict__ bsum, int n) {
  __shared__ int sd[256];
  int tid = threadIdx.x;
  int base = blockIdx.x * 1024 + tid * 4;
  int v0 = 0, v1 = 0, v2 = 0, v3 = 0;
  if (base + 0 < n) v0 = cnt[base + 0];
  if (base + 1 < n) v1 = cnt[base + 1];
  if (base + 2 < n) v2 = cnt[base + 2];
  if (base + 3 < n) v3 = cnt[base + 3];
  int tsum = v0 + v1 + v2 + v3;
  sd[tid] = tsum;
  __syncthreads();
  for (int o = 1; o < 256; o <<= 1) {
    int xv = 0;
    if (tid >= o) xv = sd[tid - o];
    __syncthreads();
    sd[tid] += xv;
    __syncthreads();
  }
  int ex = sd[tid] - tsum;
  if (base + 0 < n) off[base + 0] = ex;
  if (base + 1 < n) off[base + 1] = ex + v0;
  if (base + 2 < n) off[base + 2] = ex + v0 + v1;
  if (base + 3 < n) off[base + 3] = ex + v0 + v1 + v2;
  if (tid == 255) bsum[blockIdx.x] = sd[255];
}

__global__ __launch_bounds__(256) void scan2_kernel(int* __restrict__ bsum, int nb) {
  __shared__ int sd[256];
  int tid = threadIdx.x;
  int base = tid * 4;
  int v0 = 0, v1 = 0, v2 = 0, v3 = 0;
  if (base + 0 < nb) v0 = bsum[base + 0];
  if (base + 1 < nb) v1 = bsum[base + 1];
  if (base + 2 < nb) v2 = bsum[base + 2];
  if (base + 3 < nb) v3 = bsum[base + 3];
  int tsum = v0 + v1 + v2 + v3;
  sd[tid] = tsum;
  __syncthreads();
  for (int o = 1; o < 256; o <<= 1) {
    int xv = 0;
    if (tid >= o) xv = sd[tid - o];
    __syncthreads();
    sd[tid] += xv;
    __syncthreads();
  }
  int ex = sd[tid] - tsum;
  if (base + 0 < nb) bsum[base + 0] = ex;
  if (base + 1 < nb) bsum[base + 1] = ex + v0;
  if (base + 2 < nb) bsum[base + 2] = ex + v0 + v1;
  if (base + 3 < nb) bsum[base + 3] = ex + v0 + v1 + v2;
}

__global__ __launch_bounds__(256) void scan3_kernel(
    int* __restrict__ off, const int* __restrict__ bsum,
    int* __restrict__ cur, int n, int tote) {
  int i = blockIdx.x * 256 + threadIdx.x;
  if (i > n) return;
  int v = (i == n) ? tote : (off[i] + bsum[i >> 10]);
  off[i] = v;
  cur[i] = v;
}

__global__ __launch_bounds__(256) void fill_kernel(
    const int* __restrict__ dsti, const int* __restrict__ srci,
    int* __restrict__ cur, int* __restrict__ pool, int ne) {
  int e = blockIdx.x * 256 + threadIdx.x;
  if (e >= ne) return;
  int pos = atomicAdd(&cur[dsti[e]], 1);
  pool[pos] = srci[e];
}

// ================= layer-0: embed-fused SAGE via MFMA =================
// mean(embed(x_s)) = xbar*Wemb + b_col (b_col gated 0 when deg==0).
// Gathers 4-byte x scalars (L2-resident) instead of 256B h rows.
// Same staging/MFMA shape as the proven sage_mfma kernel.
template <int NSEG>
__global__ __launch_bounds__(256) void sage_emb(
    const float* __restrict__ xo, const float* __restrict__ Wo, const float* __restrict__ bo,
    const float* __restrict__ x1, const float* __restrict__ W1, const float* __restrict__ bc1,
    const int* __restrict__ off1,
    const float* __restrict__ x2, const float* __restrict__ W2, const float* __restrict__ bc2,
    const int* __restrict__ off2,
    const int* __restrict__ pool,
    const u16* __restrict__ WB, const float* __restrict__ bt,
    u16* __restrict__ out, int n, float alpha) {
  constexpr int KD = (NSEG + 1) * 128;
  constexpr int ST = KD + 8;  // u16 units
  __shared__ u16 At[32 * ST];
  int tid = threadIdx.x;
  int row0 = blockIdx.x * 32;
  int row = tid >> 3, chunk = tid & 7;  // 8 threads/row, 16 features each
  int grow = row0 + row;
  bool rok = grow < n;

  // own: embed(x_own) -> At cols [NSEG*128 + chunk*16, +16)
  {
    float xv = rok ? xo[grow * 8 + chunk] : 0.f;
    const float4* w4 = (const float4*)Wo + chunk * 4;
    const float4* b4 = (const float4*)bo + chunk * 4;
    u32 o[8];
    #pragma unroll
    for (int q = 0; q < 4; ++q) {
      float4 w = w4[q], b = b4[q];
      o[2 * q + 0] = pack2(xv * w.x + b.x, xv * w.y + b.y);
      o[2 * q + 1] = pack2(xv * w.z + b.z, xv * w.w + b.w);
    }
    uint4* d = (uint4*)&At[row * ST + NSEG * 128 + chunk * 16];
    d[0] = make_uint4(o[0], o[1], o[2], o[3]);
    d[1] = make_uint4(o[4], o[5], o[6], o[7]);
  }

  // mean segments: scalar gather of x columns (batched index prefetch)
  const float* xs_[2] = {x1, x2};
  const int* offs[2] = {off1, off2};
  #pragma unroll
  for (int sg = 0; sg < NSEG; ++sg) {
    const float* xs = xs_[sg];
    int deg = 0, j0 = 0;
    if (rok) { j0 = offs[sg][grow]; deg = offs[sg][grow + 1] - j0; }
    float sum = 0.f;
    for (int jb = 0; jb < deg; jb += 4) {
      int idx[4];
      #pragma unroll
      for (int t = 0; t < 4; ++t) idx[t] = pool[j0 + min(jb + t, deg - 1)];
      float v[4];
      #pragma unroll
      for (int t = 0; t < 4; ++t) v[t] = xs[idx[t] * 8 + chunk];
      #pragma unroll
      for (int t = 0; t < 4; ++t) if (jb + t < deg) sum += v[t];
    }
    float g = (deg > 0) ? 1.f : 0.f;
    float xbar = sum / fmaxf((float)deg, 1.f);
    const float4* w4 = (const float4*)(sg ? W2 : W1) + chunk * 4;
    const float4* b4 = (const float4*)(sg ? bc2 : bc1) + chunk * 4;
    u32 o[8];
    #pragma unroll
    for (int q = 0; q < 4; ++q) {
      float4 w = w4[q], b = b4[q];
      o[2 * q + 0] = pack2(xbar * w.x + g * b.x, xbar * w.y + g * b.y);
      o[2 * q + 1] = pack2(xbar * w.z + g * b.z, xbar * w.w + g * b.w);
    }
    uint4* d = (uint4*)&At[row * ST + sg * 128 + chunk * 16];
    d[0] = make_uint4(o[0], o[1], o[2], o[3]);
    d[1] = make_uint4(o[4], o[5], o[6], o[7]);
  }
  __syncthreads();

  // MFMA: wave w -> rowtile (w&1), col group 64*(w>>1), 4 coltiles of 16
  int w = tid >> 6, lane = tid & 63;
  int m16 = lane & 15, quad = lane >> 4;
  int rb = (w & 1) * 16;
  int cg = (w >> 1) * 64;
  floatx4 acc[4];
  #pragma unroll
  for (int t = 0; t < 4; ++t) acc[t] = (floatx4){0.f, 0.f, 0.f, 0.f};
  const u16* arow = &At[(rb + m16) * ST + quad * 8];
  const u16* brow = &WB[(size_t)(cg + m16) * KD + quad * 8];
  #pragma unroll 2
  for (int ks = 0; ks < KD / 32; ++ks) {
    U4S8 av; av.u = *(const uint4*)(arow + ks * 32);
    #pragma unroll
    for (int t = 0; t < 4; ++t) {
      U4S8 bv; bv.u = *(const uint4*)(brow + (size_t)t * 16 * KD + ks * 32);
      acc[t] = __builtin_amdgcn_mfma_f32_16x16x32_bf16(av.s, bv.s, acc[t], 0, 0, 0);
    }
  }
  #pragma unroll
  for (int t = 0; t < 4; ++t) {
    int col = cg + t * 16 + m16;
    float bb = bt[col];
    #pragma unroll
    for (int r = 0; r < 4; ++r) {
      int rr = row0 + rb + quad * 4 + r;
      if (rr < n) out[(size_t)rr * 128 + col] = f2bf(alpha * (acc[t][r] + bb));
    }
  }
}

// ================= layer-1: fused SAGE via MFMA, batched row gather =================
template <int NSEG>
__global__ __launch_bounds__(256) void sage_mfma(
    const u16* __restrict__ hown,
    const u16* __restrict__ hs1, const int* __restrict__ off1,
    const u16* __restrict__ hs2, const int* __restrict__ off2,
    const int* __restrict__ pool,
    const u16* __restrict__ WB, const float* __restrict__ bt,
    u16* __restrict__ out, int n, float alpha) {
  constexpr int KD = (NSEG + 1) * 128;
  constexpr int ST = KD + 8;  // u16 units
  __shared__ u16 At[32 * ST];
  int tid = threadIdx.x;
  int row0 = blockIdx.x * 32;
  int row = tid >> 3, chunk = tid & 7;  // 8 threads/row, 32B chunks
  int grow = row0 + row;
  bool rok = grow < n;

  // own segment: raw 32B bf16 copy
  {
    uint4 a0 = make_uint4(0, 0, 0, 0), a1 = a0;
    if (rok) {
      const uint4* p = (const uint4*)hown + (size_t)grow * 16 + chunk * 2;
      a0 = p[0]; a1 = p[1];
    }
    uint4* d = (uint4*)&At[row * ST + NSEG * 128 + chunk * 16];
    d[0] = a0; d[1] = a1;
  }
  // mean segments: batched gather (4 edges in flight)
  const u16* hsrc[2] = {hs1, hs2};
  const int* offs[2] = {off1, off2};
  #pragma unroll
  for (int sgi = 0; sgi < NSEG; ++sgi) {
    float a[16];
    #pragma unroll
    for (int i = 0; i < 16; ++i) a[i] = 0.f;
    int deg = 0, j0 = 0;
    if (rok) { j0 = offs[sgi][grow]; deg = offs[sgi][grow + 1] - j0; }
    const uint4* hb = (const uint4*)hsrc[sgi];
    for (int jb = 0; jb < deg; jb += 4) {
      int idx[4];
      #pragma unroll
      for (int t = 0; t < 4; ++t) idx[t] = pool[j0 + min(jb + t, deg - 1)];
      uint4 q0[4], q1[4];
      #pragma unroll
      for (int t = 0; t < 4; ++t) {
        const uint4* p = hb + (size_t)idx[t] * 16 + chunk * 2;
        q0[t] = p[0]; q1[t] = p[1];
      }
      #pragma unroll
      for (int t = 0; t < 4; ++t) {
        if (jb + t < deg) {
          float v[16];
          unpack8(q0[t], v); unpack8(q1[t], v + 8);
          #pragma unroll
          for (int i = 0; i < 16; ++i) a[i] += v[i];
        }
      }
    }
    float inv = 1.f / fmaxf((float)deg, 1.f);
    u32 o[8];
    #pragma unroll
    for (int qq = 0; qq < 8; ++qq) o[qq] = pack2(a[2 * qq] * inv, a[2 * qq + 1] * inv);
    uint4* d = (uint4*)&At[row * ST + sgi * 128 + chunk * 16];
    d[0] = make_uint4(o[0], o[1], o[2], o[3]);
    d[1] = make_uint4(o[4], o[5], o[6], o[7]);
  }
  __syncthreads();

  int w = tid >> 6, lane = tid & 63;
  int m16 = lane & 15, quad = lane >> 4;
  int rb = (w & 1) * 16;
  int cg = (w >> 1) * 64;
  floatx4 acc[4];
  #pragma unroll
  for (int t = 0; t < 4; ++t) acc[t] = (floatx4){0.f, 0.f, 0.f, 0.f};
  const u16* arow = &At[(rb + m16) * ST + quad * 8];
  const u16* brow = &WB[(size_t)(cg + m16) * KD + quad * 8];
  #pragma unroll 2
  for (int ks = 0; ks < KD / 32; ++ks) {
    U4S8 av; av.u = *(const uint4*)(arow + ks * 32);
    #pragma unroll
    for (int t = 0; t < 4; ++t) {
      U4S8 bv; bv.u = *(const uint4*)(brow + (size_t)t * 16 * KD + ks * 32);
      acc[t] = __builtin_amdgcn_mfma_f32_16x16x32_bf16(av.s, bv.s, acc[t], 0, 0, 0);
    }
  }
  #pragma unroll
  for (int t = 0; t < 4; ++t) {
    int col = cg + t * 16 + m16;
    float bb = bt[col];
    #pragma unroll
    for (int r = 0; r < 4; ++r) {
      int rr = row0 + rb + quad * 4 + r;
      if (rr < n) out[(size_t)rr * 128 + col] = f2bf(alpha * (acc[t][r] + bb));
    }
  }
}

// ---------------- head: softmax(h @ W_out + b_out) -> fp32 out ----------------
__global__ __launch_bounds__(256) void out_softmax(
    const u16* __restrict__ h, const float* __restrict__ Wout,
    const float* __restrict__ bout, float* __restrict__ out, int n) {
  __shared__ float sw[DD * OUTC];
  __shared__ float sb[OUTC];
  int tid = threadIdx.x;
  for (int i = tid; i < DD * OUTC; i += 256) sw[i] = Wout[i];
  if (tid < OUTC) sb[tid] = bout[tid];
  __syncthreads();
  int row = blockIdx.x * 256 + tid;
  if (row >= n) return;
  float logit[OUTC];
  #pragma unroll
  for (int o = 0; o < OUTC; ++o) logit[o] = sb[o];
  const uint4* hp = (const uint4*)h + (size_t)row * 16;
  for (int k = 0; k < DD; k += 8) {
    float v[8];
    unpack8(hp[k >> 3], v);
    #pragma unroll
    for (int j = 0; j < 8; ++j) {
      #pragma unroll
      for (int o = 0; o < OUTC; ++o) logit[o] += v[j] * sw[(k + j) * OUTC + o];
    }
  }
  float m = logit[0];
  #pragma unroll
  for (int o = 1; o < OUTC; ++o) m = fmaxf(m, logit[o]);
  float s = 0.f;
  #pragma unroll
  for (int o = 0; o < OUTC; ++o) { logit[o] = __expf(logit[o] - m); s += logit[o]; }
  float invs = 1.0f / s;
  #pragma unroll
  for (int o = 0; o < OUTC; ++o) out[(size_t)row * OUTC + o] = logit[o] * invs;
}

extern "C" void kernel_launch(void* const* d_in, const int* in_sizes, int n_in,
                              void* d_out, int out_size, void* d_ws, size_t ws_size,
                              hipStream_t stream) {
  const float* x_c   = (const float*)d_in[0];
  const float* x_t   = (const float*)d_in[1];
  const float* x_p   = (const float*)d_in[2];
  const float* W_col = (const float*)d_in[3];
  const float* b_col = (const float*)d_in[4];
  const float* Wn    = (const float*)d_in[5];
  const float* Wr    = (const float*)d_in[6];
  const float* b_lin = (const float*)d_in[7];
  const float* W_out = (const float*)d_in[8];
  const float* b_out = (const float*)d_in[9];
  const int* e_m_src = (const int*)d_in[10];
  const int* e_m_dst = (const int*)d_in[11];
  const int* e_i_src = (const int*)d_in[12];
  const int* e_i_dst = (const int*)d_in[13];
  float* out = (float*)d_out;

  // ---- workspace carve-out (~132 MB) ----
  size_t cursor = 0;
  char* base = (char*)d_ws;
  auto alloc = [&](size_t bytes) {
    void* p = base + cursor;
    cursor += (bytes + 255) & ~(size_t)255;
    return p;
  };
  u16* h_t  = (u16*)alloc((size_t)NTV * DD * 2);
  u16* h_cB = (u16*)alloc((size_t)NCV * DD * 2);
  u16* h_pB = (u16*)alloc((size_t)NPV * DD * 2);
  int* pool = (int*)alloc((size_t)TOTE * 4);
  int* cnt  = (int*)alloc((size_t)NTOT * 4);
  int* off  = (int*)alloc((size_t)(NTOT + 1) * 4);
  int* cur  = (int*)alloc((size_t)(NTOT + 1) * 4);
  int* bsum = (int*)alloc(1024 * 4);
  u16* WB2a = (u16*)alloc((size_t)128 * 384 * 2);
  u16* WB2b = (u16*)alloc((size_t)128 * 384 * 2);
  u16* WB1c = (u16*)alloc((size_t)128 * 256 * 2);
  u16* WB1p = (u16*)alloc((size_t)128 * 256 * 2);
  float* bt2a = (float*)alloc(128 * 4);
  float* bt2b = (float*)alloc(128 * 4);
  float* bt1c = (float*)alloc(128 * 4);
  float* bt1p = (float*)alloc(128 * 4);

  // CSR seg bases: seg0 [0,NT): t<-c (makes); seg1 [NT,2NT): t<-p (in);
  // seg2 [2NT,2NT+NC): c<-t (makes); seg3: p<-t (in).
  const int S0 = 0, S1 = NTV, S2 = 2 * NTV, S3 = 2 * NTV + NCV;

  const float* Wn_l[2][4]; const float* Wr_l[2][4]; const float* b_l[2][4];
  for (int l = 0; l < 2; ++l)
    for (int r = 0; r < 4; ++r) {
      Wn_l[l][r] = Wn + (size_t)(l * 4 + r) * DD * DD;
      Wr_l[l][r] = Wr + (size_t)(l * 4 + r) * DD * DD;
      b_l[l][r]  = b_lin + (size_t)(l * 4 + r) * DD;
    }

  int gEM = (EMV + 255) / 256, gEI = (EIV + 255) / 256;

  // ---- weight prep ----
  prep_w2<<<192, 256, 0, stream>>>(Wn_l[0][0], Wn_l[0][2], Wr_l[0][0], Wr_l[0][2],
                                   b_l[0][0], b_l[0][2], WB2a, bt2a);
  prep_w2<<<192, 256, 0, stream>>>(Wn_l[1][0], Wn_l[1][2], Wr_l[1][0], Wr_l[1][2],
                                   b_l[1][0], b_l[1][2], WB2b, bt2b);
  prep_w1<<<128, 256, 0, stream>>>(Wn_l[0][1], Wr_l[0][1], b_l[0][1], WB1c, bt1c);
  prep_w1<<<128, 256, 0, stream>>>(Wn_l[0][3], Wr_l[0][3], b_l[0][3], WB1p, bt1p);

  // ---- CSR build ----
  hipMemsetAsync(cnt, 0, (size_t)NTOT * 4, stream);
  count_kernel<<<gEM, 256, 0, stream>>>(e_m_dst, cnt + S0, EMV);
  count_kernel<<<gEI, 256, 0, stream>>>(e_i_dst, cnt + S1, EIV);
  count_kernel<<<gEM, 256, 0, stream>>>(e_m_src, cnt + S2, EMV);
  count_kernel<<<gEI, 256, 0, stream>>>(e_i_src, cnt + S3, EIV);
  int nblk = (NTOT + 1023) / 1024;  // 733
  scan1_kernel<<<nblk, 256, 0, stream>>>(cnt, off, bsum, NTOT);
  scan2_kernel<<<1, 256, 0, stream>>>(bsum, nblk);
  scan3_kernel<<<(NTOT + 1 + 255) / 256, 256, 0, stream>>>(off, bsum, cur, NTOT, TOTE);
  fill_kernel<<<gEM, 256, 0, stream>>>(e_m_dst, e_m_src, cur + S0, pool, EMV);
  fill_kernel<<<gEI, 256, 0, stream>>>(e_i_dst, e_i_src, cur + S1, pool, EIV);
  fill_kernel<<<gEM, 256, 0, stream>>>(e_m_src, e_m_dst, cur + S2, pool, EMV);
  fill_kernel<<<gEI, 256, 0, stream>>>(e_i_src, e_i_dst, cur + S3, pool, EIV);

  int gT = NTV / 32, gC = NCV / 32, gP = (NPV + 31) / 32;
  const float* Wc0 = W_col + 0 * DD; const float* bc0 = b_col + 0 * DD;  // customer
  const float* Wc1 = W_col + 1 * DD; const float* bc1 = b_col + 1 * DD;  // transaction
  const float* Wc2 = W_col + 2 * DD; const float* bc2 = b_col + 2 * DD;  // product

  // ---- layer 0 (embed fused; gathers 4B scalars from L2-resident x) ----
  sage_emb<1><<<gC, 256, 0, stream>>>(x_c, Wc0, bc0,
                                      x_t, Wc1, bc1, off + S2,
                                      nullptr, nullptr, nullptr, nullptr,
                                      pool, WB1c, bt1c, h_cB, NCV, 1.0f);
  sage_emb<1><<<gP, 256, 0, stream>>>(x_p, Wc2, bc2,
                                      x_t, Wc1, bc1, off + S3,
                                      nullptr, nullptr, nullptr, nullptr,
                                      pool, WB1p, bt1p, h_pB, NPV, 1.0f);
  sage_emb<2><<<gT, 256, 0, stream>>>(x_t, Wc1, bc1,
                                      x_c, Wc0, bc0, off + S0,
                                      x_p, Wc2, bc2, off + S1,
                                      pool, WB2a, bt2a, h_t, NTV, 0.5f);

  // ---- layer 1 (only h_t live downstream; in-place h_t update) ----
  sage_mfma<2><<<gT, 256, 0, stream>>>(h_t, h_cB, off + S0, h_pB, off + S1, pool,
                                       WB2b, bt2b, h_t, NTV, 0.5f);

  // ---- head ----
  out_softmax<<<(NTV + 255) / 256, 256, 0, stream>>>(h_t, W_out, b_out, out, NTV);
}

// Round 11
// 895.301 us; speedup vs baseline: 1.3811x; 1.0767x over previous
//
#include <hip/hip_runtime.h>

#define NCV 100000
#define NTV 300000
#define NPV 50000
#define DD 128
#define OUTC 10
#define EMV 300000
#define EIV 600000
#define NTOT (2 * NTV + NCV + NPV)      // 750000 concatenated count slots
#define TOTE (2 * (EMV + EIV))          // 1800000 pool entries

typedef unsigned short u16;
typedef unsigned int u32;
typedef __attribute__((ext_vector_type(8))) short short8;   // 8 bf16 (4 VGPRs)
typedef __attribute__((ext_vector_type(4))) float floatx4;  // MFMA accumulator

union U4S8 { uint4 u; short8 s; };

__device__ __forceinline__ u16 f2bf(float f) {
  u32 x = __float_as_uint(f);
  return (u16)((x + 0x7fffu + ((x >> 16) & 1u)) >> 16);
}
__device__ __forceinline__ u32 pack2(float a, float b) {
  return (u32)f2bf(a) | ((u32)f2bf(b) << 16);
}
__device__ __forceinline__ void unpack8(uint4 q, float* v) {
  v[0] = __uint_as_float(q.x << 16); v[1] = __uint_as_float(q.x & 0xffff0000u);
  v[2] = __uint_as_float(q.y << 16); v[3] = __uint_as_float(q.y & 0xffff0000u);
  v[4] = __uint_as_float(q.z << 16); v[5] = __uint_as_float(q.z & 0xffff0000u);
  v[6] = __uint_as_float(q.w << 16); v[7] = __uint_as_float(q.w & 0xffff0000u);
}

// ---------------- weight prep: permuted B layout ----------------
// Stored row n' = g*64 + t*16 + m16 holds NATURAL col c = g*64 + 4*(n'&15) + t,
// so each MFMA lane's 4 D-cols are contiguous -> packed 8B stores.
__device__ __forceinline__ int permcol(int np) {
  return (np & ~63) + 4 * (np & 15) + ((np >> 4) & 3);
}

__global__ __launch_bounds__(256) void prep_w2(
    const float* __restrict__ Wn0, const float* __restrict__ Wn2,
    const float* __restrict__ Wr0, const float* __restrict__ Wr2,
    const float* __restrict__ b0, const float* __restrict__ b2,
    u16* __restrict__ WB, float* __restrict__ bt) {
  int i = blockIdx.x * 256 + threadIdx.x;
  if (i >= 128 * 384) return;
  int np = i / 384, k = i % 384;
  int c = permcol(np);
  float v;
  if (k < 128) v = Wn0[k * 128 + c];
  else if (k < 256) v = Wn2[(k - 128) * 128 + c];
  else v = Wr0[(k - 256) * 128 + c] + Wr2[(k - 256) * 128 + c];
  WB[i] = f2bf(v);
  if (i < 128) bt[i] = b0[i] + b2[i];
}

__global__ __launch_bounds__(256) void prep_w1(
    const float* __restrict__ Wn, const float* __restrict__ Wr,
    const float* __restrict__ b, u16* __restrict__ WB, float* __restrict__ bt) {
  int i = blockIdx.x * 256 + threadIdx.x;
  if (i >= 128 * 256) return;
  int np = i / 256, k = i % 256;
  int c = permcol(np);
  float v = (k < 128) ? Wn[k * 128 + c] : Wr[(k - 128) * 128 + c];
  WB[i] = f2bf(v);
  if (i < 128) bt[i] = b[i];
}

// ---------------- CSR build ----------------
__global__ __launch_bounds__(256) void count_kernel(
    const int* __restrict__ idxs, int* __restrict__ cnt, int ne) {
  int e = blockIdx.x * 256 + threadIdx.x;
  if (e < ne) atomicAdd(&cnt[idxs[e]], 1);
}

__global__ __launch_bounds__(256) void scan1_kernel(
    const int* __restrict__ cnt, int* __restrict__ off,
    int* __restrict__ bsum, int n) {
  __shared__ int sd[256];
  int tid = threadIdx.x;
  int base = blockIdx.x * 1024 + tid * 4;
  int v0 = 0, v1 = 0, v2 = 0, v3 = 0;
  if (base + 0 < n) v0 = cnt[base + 0];
  if (base + 1 < n) v1 = cnt[base + 1];
  if (base + 2 < n) v2 = cnt[base + 2];
  if (base + 3 < n) v3 = cnt[base + 3];
  int tsum = v0 + v1 + v2 + v3;
  sd[tid] = tsum;
  __syncthreads();
  for (int o = 1; o < 256; o <<= 1) {
    int xv = 0;
    if (tid >= o) xv = sd[tid - o];
    __syncthreads();
    sd[tid] += xv;
    __syncthreads();
  }
  int ex = sd[tid] - tsum;
  if (base + 0 < n) off[base + 0] = ex;
  if (base + 1 < n) off[base + 1] = ex + v0;
  if (base + 2 < n) off[base + 2] = ex + v0 + v1;
  if (base + 3 < n) off[base + 3] = ex + v0 + v1 + v2;
  if (tid == 255) bsum[blockIdx.x] = sd[255];
}

__global__ __launch_bounds__(256) void scan2_kernel(int* __restrict__ bsum, int nb) {
  __shared__ int sd[256];
  int tid = threadIdx.x;
  int base = tid * 4;
  int v0 = 0, v1 = 0, v2 = 0, v3 = 0;
  if (base + 0 < nb) v0 = bsum[base + 0];
  if (base + 1 < nb) v1 = bsum[base + 1];
  if (base + 2 < nb) v2 = bsum[base + 2];
  if (base + 3 < nb) v3 = bsum[base + 3];
  int tsum = v0 + v1 + v2 + v3;
  sd[tid] = tsum;
  __syncthreads();
  for (int o = 1; o < 256; o <<= 1) {
    int xv = 0;
    if (tid >= o) xv = sd[tid - o];
    __syncthreads();
    sd[tid] += xv;
    __syncthreads();
  }
  int ex = sd[tid] - tsum;
  if (base + 0 < nb) bsum[base + 0] = ex;
  if (base + 1 < nb) bsum[base + 1] = ex + v0;
  if (base + 2 < nb) bsum[base + 2] = ex + v0 + v1;
  if (base + 3 < nb) bsum[base + 3] = ex + v0 + v1 + v2;
}

__global__ __launch_bounds__(256) void scan3_kernel(
    int* __restrict__ off, const int* __restrict__ bsum,
    int* __restrict__ cur, int n, int tote) {
  int i = blockIdx.x * 256 + threadIdx.x;
  if (i > n) return;
  int v = (i == n) ? tote : (off[i] + bsum[i >> 10]);
  off[i] = v;
  cur[i] = v;
}

__global__ __launch_bounds__(256) void fill_kernel(
    const int* __restrict__ dsti, const int* __restrict__ srci,
    int* __restrict__ cur, int* __restrict__ pool, int ne) {
  int e = blockIdx.x * 256 + threadIdx.x;
  if (e >= ne) return;
  int pos = atomicAdd(&cur[dsti[e]], 1);
  pool[pos] = srci[e];
}

// ================= layer-0 (c,p): embed-fused SAGE via MFMA, packed stores =================
__global__ __launch_bounds__(256) void sage_emb1(
    const float* __restrict__ xo, const float* __restrict__ Wo, const float* __restrict__ bo,
    const float* __restrict__ x1, const float* __restrict__ W1, const float* __restrict__ bc1,
    const int* __restrict__ off1, const int* __restrict__ pool,
    const u16* __restrict__ WB, const float* __restrict__ bt,
    u16* __restrict__ out, int n) {
  constexpr int KD = 256;
  constexpr int ST = KD + 8;
  __shared__ u16 At[32 * ST];
  int tid = threadIdx.x;
  int row0 = blockIdx.x * 32;
  int row = tid >> 3, chunk = tid & 7;
  int grow = row0 + row;
  bool rok = grow < n;

  // own embed -> At cols 128..255
  {
    float xv = rok ? xo[grow * 8 + chunk] : 0.f;
    const float4* w4 = (const float4*)Wo + chunk * 4;
    const float4* b4 = (const float4*)bo + chunk * 4;
    u32 o[8];
    #pragma unroll
    for (int q = 0; q < 4; ++q) {
      float4 w = w4[q], b = b4[q];
      o[2 * q + 0] = pack2(xv * w.x + b.x, xv * w.y + b.y);
      o[2 * q + 1] = pack2(xv * w.z + b.z, xv * w.w + b.w);
    }
    uint4* d = (uint4*)&At[row * ST + 128 + chunk * 16];
    d[0] = make_uint4(o[0], o[1], o[2], o[3]);
    d[1] = make_uint4(o[4], o[5], o[6], o[7]);
  }
  // mean: scalar gather of x columns
  {
    int deg = 0, j0 = 0;
    if (rok) { j0 = off1[grow]; deg = off1[grow + 1] - j0; }
    float sum = 0.f;
    for (int jb = 0; jb < deg; jb += 4) {
      int idx[4];
      #pragma unroll
      for (int t = 0; t < 4; ++t) idx[t] = pool[j0 + min(jb + t, deg - 1)];
      float v[4];
      #pragma unroll
      for (int t = 0; t < 4; ++t) v[t] = x1[idx[t] * 8 + chunk];
      #pragma unroll
      for (int t = 0; t < 4; ++t) if (jb + t < deg) sum += v[t];
    }
    float g = (deg > 0) ? 1.f : 0.f;
    float xbar = sum / fmaxf((float)deg, 1.f);
    const float4* w4 = (const float4*)W1 + chunk * 4;
    const float4* b4 = (const float4*)bc1 + chunk * 4;
    u32 o[8];
    #pragma unroll
    for (int q = 0; q < 4; ++q) {
      float4 w = w4[q], b = b4[q];
      o[2 * q + 0] = pack2(xbar * w.x + g * b.x, xbar * w.y + g * b.y);
      o[2 * q + 1] = pack2(xbar * w.z + g * b.z, xbar * w.w + g * b.w);
    }
    uint4* d = (uint4*)&At[row * ST + chunk * 16];
    d[0] = make_uint4(o[0], o[1], o[2], o[3]);
    d[1] = make_uint4(o[4], o[5], o[6], o[7]);
  }
  __syncthreads();

  int w = tid >> 6, lane = tid & 63;
  int m16 = lane & 15, quad = lane >> 4;
  int rb = (w & 1) * 16;
  int cg = (w >> 1) * 64;
  floatx4 acc[4];
  #pragma unroll
  for (int t = 0; t < 4; ++t) acc[t] = (floatx4){0.f, 0.f, 0.f, 0.f};
  const u16* arow = &At[(rb + m16) * ST + quad * 8];
  const u16* brow = &WB[(size_t)(cg + m16) * KD + quad * 8];
  #pragma unroll 2
  for (int ks = 0; ks < KD / 32; ++ks) {
    U4S8 av; av.u = *(const uint4*)(arow + ks * 32);
    #pragma unroll
    for (int t = 0; t < 4; ++t) {
      U4S8 bv; bv.u = *(const uint4*)(brow + (size_t)t * 16 * KD + ks * 32);
      acc[t] = __builtin_amdgcn_mfma_f32_16x16x32_bf16(av.s, bv.s, acc[t], 0, 0, 0);
    }
  }
  // packed epilogue: lane's natural cols c0..c0+3 (permuted WB)
  int c0 = cg + 4 * m16;
  float bb0 = bt[c0], bb1 = bt[c0 + 1], bb2 = bt[c0 + 2], bb3 = bt[c0 + 3];
  #pragma unroll
  for (int r = 0; r < 4; ++r) {
    int rr = row0 + rb + quad * 4 + r;
    if (rr < n) {
      uint2 st;
      st.x = pack2(acc[0][r] + bb0, acc[1][r] + bb1);
      st.y = pack2(acc[2][r] + bb2, acc[3][r] + bb3);
      *(uint2*)&out[(size_t)rr * 128 + c0] = st;
    }
  }
}

// ================= fused transaction pipeline =================
// Phase A: layer-0 embed-SAGE (KD=384, WBa) -> h0 kept in LDS
// Phase B: layer-1 SAGE (means from h_cB/h_pB, own = h0; KD=384, WBb)
// Head: logits partial per wave (64 cols) -> LDS combine -> softmax -> out fp32
__global__ __launch_bounds__(256) void fused_t(
    const float* __restrict__ xo, const float* __restrict__ Wo, const float* __restrict__ bo,
    const float* __restrict__ x1, const float* __restrict__ W1, const float* __restrict__ bc1,
    const int* __restrict__ off1,
    const float* __restrict__ x2, const float* __restrict__ W2, const float* __restrict__ bc2,
    const int* __restrict__ off2,
    const u16* __restrict__ hs1, const u16* __restrict__ hs2,
    const int* __restrict__ pool,
    const u16* __restrict__ WBa, const float* __restrict__ bta,
    const u16* __restrict__ WBb, const float* __restrict__ btb,
    const float* __restrict__ Wout, const float* __restrict__ bout,
    float* __restrict__ out, int n) {
  constexpr int KD = 384;
  constexpr int ST = KD + 8;
  __shared__ u16 At[32 * ST];        // 25,088 B
  __shared__ float sw[DD * OUTC];    // 5,120 B
  __shared__ float Part[32][2 * OUTC];  // 2,560 B -> total exactly 32 KB
  int tid = threadIdx.x;
  int row0 = blockIdx.x * 32;
  int row = tid >> 3, chunk = tid & 7;
  int grow = row0 + row;
  bool rok = grow < n;

  for (int i = tid; i < DD * OUTC; i += 256) sw[i] = Wout[i];

  // ---- Phase A staging: embeds from x scalars ----
  {
    float xv = rok ? xo[grow * 8 + chunk] : 0.f;
    const float4* w4 = (const float4*)Wo + chunk * 4;
    const float4* b4 = (const float4*)bo + chunk * 4;
    u32 o[8];
    #pragma unroll
    for (int q = 0; q < 4; ++q) {
      float4 w = w4[q], b = b4[q];
      o[2 * q + 0] = pack2(xv * w.x + b.x, xv * w.y + b.y);
      o[2 * q + 1] = pack2(xv * w.z + b.z, xv * w.w + b.w);
    }
    uint4* d = (uint4*)&At[row * ST + 256 + chunk * 16];
    d[0] = make_uint4(o[0], o[1], o[2], o[3]);
    d[1] = make_uint4(o[4], o[5], o[6], o[7]);
  }
  const float* xs_[2] = {x1, x2};
  const float* Ws_[2] = {W1, W2};
  const float* bs_[2] = {bc1, bc2};
  const int* offs[2] = {off1, off2};
  #pragma unroll
  for (int sg = 0; sg < 2; ++sg) {
    int deg = 0, j0 = 0;
    if (rok) { j0 = offs[sg][grow]; deg = offs[sg][grow + 1] - j0; }
    float sum = 0.f;
    for (int jb = 0; jb < deg; jb += 4) {
      int idx[4];
      #pragma unroll
      for (int t = 0; t < 4; ++t) idx[t] = pool[j0 + min(jb + t, deg - 1)];
      float v[4];
      #pragma unroll
      for (int t = 0; t < 4; ++t) v[t] = xs_[sg][idx[t] * 8 + chunk];
      #pragma unroll
      for (int t = 0; t < 4; ++t) if (jb + t < deg) sum += v[t];
    }
    float g = (deg > 0) ? 1.f : 0.f;
    float xbar = sum / fmaxf((float)deg, 1.f);
    const float4* w4 = (const float4*)Ws_[sg] + chunk * 4;
    const float4* b4 = (const float4*)bs_[sg] + chunk * 4;
    u32 o[8];
    #pragma unroll
    for (int q = 0; q < 4; ++q) {
      float4 w = w4[q], b = b4[q];
      o[2 * q + 0] = pack2(xbar * w.x + g * b.x, xbar * w.y + g * b.y);
      o[2 * q + 1] = pack2(xbar * w.z + g * b.z, xbar * w.w + g * b.w);
    }
    uint4* d = (uint4*)&At[row * ST + sg * 128 + chunk * 16];
    d[0] = make_uint4(o[0], o[1], o[2], o[3]);
    d[1] = make_uint4(o[4], o[5], o[6], o[7]);
  }
  __syncthreads();

  // ---- MFMA-A ----
  int w = tid >> 6, lane = tid & 63;
  int m16 = lane & 15, quad = lane >> 4;
  int rb = (w & 1) * 16;
  int cg = (w >> 1) * 64;
  floatx4 acc[4];
  #pragma unroll
  for (int t = 0; t < 4; ++t) acc[t] = (floatx4){0.f, 0.f, 0.f, 0.f};
  {
    const u16* arow = &At[(rb + m16) * ST + quad * 8];
    const u16* brow = &WBa[(size_t)(cg + m16) * KD + quad * 8];
    #pragma unroll 2
    for (int ks = 0; ks < KD / 32; ++ks) {
      U4S8 av; av.u = *(const uint4*)(arow + ks * 32);
      #pragma unroll
      for (int t = 0; t < 4; ++t) {
        U4S8 bv; bv.u = *(const uint4*)(brow + (size_t)t * 16 * KD + ks * 32);
        acc[t] = __builtin_amdgcn_mfma_f32_16x16x32_bf16(av.s, bv.s, acc[t], 0, 0, 0);
      }
    }
  }
  __syncthreads();  // all At reads done before overwrite

  // ---- h0 -> At own segment (cols 256..383), packed ds_write ----
  {
    int c0 = cg + 4 * m16;
    float ba0 = bta[c0], ba1 = bta[c0 + 1], ba2 = bta[c0 + 2], ba3 = bta[c0 + 3];
    #pragma unroll
    for (int r = 0; r < 4; ++r) {
      int lr = rb + quad * 4 + r;
      uint2 st;
      st.x = pack2(0.5f * (acc[0][r] + ba0), 0.5f * (acc[1][r] + ba1));
      st.y = pack2(0.5f * (acc[2][r] + ba2), 0.5f * (acc[3][r] + ba3));
      *(uint2*)&At[lr * ST + 256 + c0] = st;
    }
  }

  // ---- Phase B staging: vector gather of h_cB / h_pB rows ----
  const u16* hsrc[2] = {hs1, hs2};
  #pragma unroll
  for (int sg = 0; sg < 2; ++sg) {
    float a[16];
    #pragma unroll
    for (int i = 0; i < 16; ++i) a[i] = 0.f;
    int deg = 0, j0 = 0;
    if (rok) { j0 = offs[sg][grow]; deg = offs[sg][grow + 1] - j0; }
    const uint4* hb = (const uint4*)hsrc[sg];
    for (int jb = 0; jb < deg; jb += 4) {
      int idx[4];
      #pragma unroll
      for (int t = 0; t < 4; ++t) idx[t] = pool[j0 + min(jb + t, deg - 1)];
      uint4 q0[4], q1[4];
      #pragma unroll
      for (int t = 0; t < 4; ++t) {
        const uint4* p = hb + (size_t)idx[t] * 16 + chunk * 2;
        q0[t] = p[0]; q1[t] = p[1];
      }
      #pragma unroll
      for (int t = 0; t < 4; ++t) {
        if (jb + t < deg) {
          float v[16];
          unpack8(q0[t], v); unpack8(q1[t], v + 8);
          #pragma unroll
          for (int i = 0; i < 16; ++i) a[i] += v[i];
        }
      }
    }
    float inv = 1.f / fmaxf((float)deg, 1.f);
    u32 o[8];
    #pragma unroll
    for (int qq = 0; qq < 8; ++qq) o[qq] = pack2(a[2 * qq] * inv, a[2 * qq + 1] * inv);
    uint4* d = (uint4*)&At[row * ST + sg * 128 + chunk * 16];
    d[0] = make_uint4(o[0], o[1], o[2], o[3]);
    d[1] = make_uint4(o[4], o[5], o[6], o[7]);
  }
  __syncthreads();

  // ---- MFMA-B ----
  floatx4 acm[4];
  #pragma unroll
  for (int t = 0; t < 4; ++t) acm[t] = (floatx4){0.f, 0.f, 0.f, 0.f};
  {
    const u16* arow = &At[(rb + m16) * ST + quad * 8];
    const u16* brow = &WBb[(size_t)(cg + m16) * KD + quad * 8];
    #pragma unroll 2
    for (int ks = 0; ks < KD / 32; ++ks) {
      U4S8 av; av.u = *(const uint4*)(arow + ks * 32);
      #pragma unroll
      for (int t = 0; t < 4; ++t) {
        U4S8 bv; bv.u = *(const uint4*)(brow + (size_t)t * 16 * KD + ks * 32);
        acm[t] = __builtin_amdgcn_mfma_f32_16x16x32_bf16(av.s, bv.s, acm[t], 0, 0, 0);
      }
    }
  }

  // ---- head: per-wave 64-col partial logits -> LDS combine (fix for the
  //      half-sum bug: each wave only covers cols [cg, cg+64)) ----
  {
    int c0 = cg + 4 * m16;
    int cgi = w >> 1;  // col-group index 0/1
    float bb[4] = {btb[c0], btb[c0 + 1], btb[c0 + 2], btb[c0 + 3]};
    float wreg[4][OUTC];
    #pragma unroll
    for (int t = 0; t < 4; ++t)
      #pragma unroll
      for (int o = 0; o < OUTC; ++o) wreg[t][o] = sw[(c0 + t) * OUTC + o];
    #pragma unroll
    for (int r = 0; r < 4; ++r) {
      float lg[OUTC];
      #pragma unroll
      for (int o = 0; o < OUTC; ++o) lg[o] = 0.f;
      #pragma unroll
      for (int t = 0; t < 4; ++t) {
        float hv = 0.5f * (acm[t][r] + bb[t]);
        #pragma unroll
        for (int o = 0; o < OUTC; ++o) lg[o] += hv * wreg[t][o];
      }
      #pragma unroll
      for (int o = 0; o < OUTC; ++o) {
        lg[o] += __shfl_xor(lg[o], 1);
        lg[o] += __shfl_xor(lg[o], 2);
        lg[o] += __shfl_xor(lg[o], 4);
        lg[o] += __shfl_xor(lg[o], 8);
      }
      if (m16 == 0) {
        int lr = rb + quad * 4 + r;
        #pragma unroll
        for (int o = 0; o < OUTC; ++o) Part[lr][cgi * OUTC + o] = lg[o];
      }
    }
  }
  __syncthreads();

  // ---- final combine + softmax by threads 0..31 ----
  if (tid < 32) {
    int rr = row0 + tid;
    if (rr < n) {
      float lg[OUTC];
      #pragma unroll
      for (int o = 0; o < OUTC; ++o)
        lg[o] = Part[tid][o] + Part[tid][OUTC + o] + bout[o];
      float m = lg[0];
      #pragma unroll
      for (int o = 1; o < OUTC; ++o) m = fmaxf(m, lg[o]);
      float s = 0.f;
      #pragma unroll
      for (int o = 0; o < OUTC; ++o) { lg[o] = __expf(lg[o] - m); s += lg[o]; }
      float invs = 1.0f / s;
      float* op = &out[(size_t)rr * OUTC];
      #pragma unroll
      for (int o = 0; o < 5; ++o) {
        float2 p2; p2.x = lg[2 * o] * invs; p2.y = lg[2 * o + 1] * invs;
        *(float2*)&op[2 * o] = p2;
      }
    }
  }
}

extern "C" void kernel_launch(void* const* d_in, const int* in_sizes, int n_in,
                              void* d_out, int out_size, void* d_ws, size_t ws_size,
                              hipStream_t stream) {
  const float* x_c   = (const float*)d_in[0];
  const float* x_t   = (const float*)d_in[1];
  const float* x_p   = (const float*)d_in[2];
  const float* W_col = (const float*)d_in[3];
  const float* b_col = (const float*)d_in[4];
  const float* Wn    = (const float*)d_in[5];
  const float* Wr    = (const float*)d_in[6];
  const float* b_lin = (const float*)d_in[7];
  const float* W_out = (const float*)d_in[8];
  const float* b_out = (const float*)d_in[9];
  const int* e_m_src = (const int*)d_in[10];
  const int* e_m_dst = (const int*)d_in[11];
  const int* e_i_src = (const int*)d_in[12];
  const int* e_i_dst = (const int*)d_in[13];
  float* out = (float*)d_out;

  // ---- workspace carve-out (~56 MB) ----
  size_t cursor = 0;
  char* base = (char*)d_ws;
  auto alloc = [&](size_t bytes) {
    void* p = base + cursor;
    cursor += (bytes + 255) & ~(size_t)255;
    return p;
  };
  u16* h_cB = (u16*)alloc((size_t)NCV * DD * 2);
  u16* h_pB = (u16*)alloc((size_t)NPV * DD * 2);
  int* pool = (int*)alloc((size_t)TOTE * 4);
  int* cnt  = (int*)alloc((size_t)NTOT * 4);
  int* off  = (int*)alloc((size_t)(NTOT + 1) * 4);
  int* cur  = (int*)alloc((size_t)(NTOT + 1) * 4);
  int* bsum = (int*)alloc(1024 * 4);
  u16* WB2a = (u16*)alloc((size_t)128 * 384 * 2);
  u16* WB2b = (u16*)alloc((size_t)128 * 384 * 2);
  u16* WB1c = (u16*)alloc((size_t)128 * 256 * 2);
  u16* WB1p = (u16*)alloc((size_t)128 * 256 * 2);
  float* bt2a = (float*)alloc(128 * 4);
  float* bt2b = (float*)alloc(128 * 4);
  float* bt1c = (float*)alloc(128 * 4);
  float* bt1p = (float*)alloc(128 * 4);

  // CSR seg bases: seg0 [0,NT): t<-c (makes); seg1 [NT,2NT): t<-p (in);
  // seg2 [2NT,2NT+NC): c<-t (makes); seg3: p<-t (in).
  const int S0 = 0, S1 = NTV, S2 = 2 * NTV, S3 = 2 * NTV + NCV;

  const float* Wn_l[2][4]; const float* Wr_l[2][4]; const float* b_l[2][4];
  for (int l = 0; l < 2; ++l)
    for (int r = 0; r < 4; ++r) {
      Wn_l[l][r] = Wn + (size_t)(l * 4 + r) * DD * DD;
      Wr_l[l][r] = Wr + (size_t)(l * 4 + r) * DD * DD;
      b_l[l][r]  = b_lin + (size_t)(l * 4 + r) * DD;
    }

  int gEM = (EMV + 255) / 256, gEI = (EIV + 255) / 256;

  // ---- weight prep ----
  prep_w2<<<192, 256, 0, stream>>>(Wn_l[0][0], Wn_l[0][2], Wr_l[0][0], Wr_l[0][2],
                                   b_l[0][0], b_l[0][2], WB2a, bt2a);
  prep_w2<<<192, 256, 0, stream>>>(Wn_l[1][0], Wn_l[1][2], Wr_l[1][0], Wr_l[1][2],
                                   b_l[1][0], b_l[1][2], WB2b, bt2b);
  prep_w1<<<128, 256, 0, stream>>>(Wn_l[0][1], Wr_l[0][1], b_l[0][1], WB1c, bt1c);
  prep_w1<<<128, 256, 0, stream>>>(Wn_l[0][3], Wr_l[0][3], b_l[0][3], WB1p, bt1p);

  // ---- CSR build ----
  hipMemsetAsync(cnt, 0, (size_t)NTOT * 4, stream);
  count_kernel<<<gEM, 256, 0, stream>>>(e_m_dst, cnt + S0, EMV);
  count_kernel<<<gEI, 256, 0, stream>>>(e_i_dst, cnt + S1, EIV);
  count_kernel<<<gEM, 256, 0, stream>>>(e_m_src, cnt + S2, EMV);
  count_kernel<<<gEI, 256, 0, stream>>>(e_i_src, cnt + S3, EIV);
  int nblk = (NTOT + 1023) / 1024;  // 733
  scan1_kernel<<<nblk, 256, 0, stream>>>(cnt, off, bsum, NTOT);
  scan2_kernel<<<1, 256, 0, stream>>>(bsum, nblk);
  scan3_kernel<<<(NTOT + 1 + 255) / 256, 256, 0, stream>>>(off, bsum, cur, NTOT, TOTE);
  fill_kernel<<<gEM, 256, 0, stream>>>(e_m_dst, e_m_src, cur + S0, pool, EMV);
  fill_kernel<<<gEI, 256, 0, stream>>>(e_i_dst, e_i_src, cur + S1, pool, EIV);
  fill_kernel<<<gEM, 256, 0, stream>>>(e_m_src, e_m_dst, cur + S2, pool, EMV);
  fill_kernel<<<gEI, 256, 0, stream>>>(e_i_src, e_i_dst, cur + S3, pool, EIV);

  int gT = NTV / 32, gC = NCV / 32, gP = (NPV + 31) / 32;
  const float* Wc0 = W_col + 0 * DD; const float* bc0 = b_col + 0 * DD;  // customer
  const float* Wc1 = W_col + 1 * DD; const float* bc1 = b_col + 1 * DD;  // transaction
  const float* Wc2 = W_col + 2 * DD; const float* bc2 = b_col + 2 * DD;  // product

  // ---- layer 0: c and p (feed layer-1 means) ----
  sage_emb1<<<gC, 256, 0, stream>>>(x_c, Wc0, bc0,
                                    x_t, Wc1, bc1, off + S2,
                                    pool, WB1c, bt1c, h_cB, NCV);
  sage_emb1<<<gP, 256, 0, stream>>>(x_p, Wc2, bc2,
                                    x_t, Wc1, bc1, off + S3,
                                    pool, WB1p, bt1p, h_pB, NPV);

  // ---- fused transaction pipeline (layer0 + layer1 + head) ----
  fused_t<<<gT, 256, 0, stream>>>(x_t, Wc1, bc1,
                                  x_c, Wc0, bc0, off + S0,
                                  x_p, Wc2, bc2, off + S1,
                                  h_cB, h_pB, pool,
                                  WB2a, bt2a, WB2b, bt2b,
                                  W_out, b_out, out, NTV);
}

// Round 13
// 396.430 us; speedup vs baseline: 3.1191x; 2.2584x over previous
//
#include <hip/hip_runtime.h>

#define NCV 100000
#define NTV 300000
#define NPV 50000
#define DD 128
#define OUTC 10
#define EMV 300000
#define EIV 600000
#define NTOT (2 * NTV + NCV + NPV)      // 750000 concatenated count slots
#define TOTE (2 * (EMV + EIV))          // 1800000 pool entries
#define ZST 20                           // z row stride (floats), 80B aligned

// ---------------- CSR build ----------------
__global__ __launch_bounds__(256) void count_kernel(
    const int* __restrict__ idxs, int* __restrict__ cnt, int ne) {
  int e = blockIdx.x * 256 + threadIdx.x;
  if (e < ne) atomicAdd(&cnt[idxs[e]], 1);
}

__global__ __launch_bounds__(256) void scan1_kernel(
    const int* __restrict__ cnt, int* __restrict__ off,
    int* __restrict__ bsum, int n) {
  __shared__ int sd[256];
  int tid = threadIdx.x;
  int base = blockIdx.x * 1024 + tid * 4;
  int v0 = 0, v1 = 0, v2 = 0, v3 = 0;
  if (base + 0 < n) v0 = cnt[base + 0];
  if (base + 1 < n) v1 = cnt[base + 1];
  if (base + 2 < n) v2 = cnt[base + 2];
  if (base + 3 < n) v3 = cnt[base + 3];
  int tsum = v0 + v1 + v2 + v3;
  sd[tid] = tsum;
  __syncthreads();
  for (int o = 1; o < 256; o <<= 1) {
    int xv = 0;
    if (tid >= o) xv = sd[tid - o];
    __syncthreads();
    sd[tid] += xv;
    __syncthreads();
  }
  int ex = sd[tid] - tsum;
  if (base + 0 < n) off[base + 0] = ex;
  if (base + 1 < n) off[base + 1] = ex + v0;
  if (base + 2 < n) off[base + 2] = ex + v0 + v1;
  if (base + 3 < n) off[base + 3] = ex + v0 + v1 + v2;
  if (tid == 255) bsum[blockIdx.x] = sd[255];
}

__global__ __launch_bounds__(256) void scan2_kernel(int* __restrict__ bsum, int nb) {
  __shared__ int sd[256];
  int tid = threadIdx.x;
  int base = tid * 4;
  int v0 = 0, v1 = 0, v2 = 0, v3 = 0;
  if (base + 0 < nb) v0 = bsum[base + 0];
  if (base + 1 < nb) v1 = bsum[base + 1];
  if (base + 2 < nb) v2 = bsum[base + 2];
  if (base + 3 < nb) v3 = bsum[base + 3];
  int tsum = v0 + v1 + v2 + v3;
  sd[tid] = tsum;
  __syncthreads();
  for (int o = 1; o < 256; o <<= 1) {
    int xv = 0;
    if (tid >= o) xv = sd[tid - o];
    __syncthreads();
    sd[tid] += xv;
    __syncthreads();
  }
  int ex = sd[tid] - tsum;
  if (base + 0 < nb) bsum[base + 0] = ex;
  if (base + 1 < nb) bsum[base + 1] = ex + v0;
  if (base + 2 < nb) bsum[base + 2] = ex + v0 + v1;
  if (base + 3 < nb) bsum[base + 3] = ex + v0 + v1 + v2;
}

__global__ __launch_bounds__(256) void scan3_kernel(
    int* __restrict__ off, const int* __restrict__ bsum,
    int* __restrict__ cur, int n, int tote) {
  int i = blockIdx.x * 256 + threadIdx.x;
  if (i > n) return;
  int v = (i == n) ? tote : (off[i] + bsum[i >> 10]);
  off[i] = v;
  cur[i] = v;
}

__global__ __launch_bounds__(256) void fill_kernel(
    const int* __restrict__ dsti, const int* __restrict__ srci,
    int* __restrict__ cur, int* __restrict__ pool, int ne) {
  int e = blockIdx.x * 256 + threadIdx.x;
  if (e >= ne) return;
  int pos = atomicAdd(&cur[dsti[e]], 1);
  pool[pos] = srci[e];
}

// ---------------- weight folding ----------------
// T1 = Wn10@Wout, T2 = Wn12@Wout, T3 = 0.5*(Wr10+Wr12)@Wout  (each 128x10)
// The 0.5 on T3 folds h_t1 = 0.5*(o_t0+o_t2): every path through T3 carries
// the inner 0.5, so downstream (Q5/Q6/Q7, (b00+b02)@T3, bT@Q7) needs only
// the uniform outer 0.5 applied in prep_B.  [round-12 bug: this was missing]
__global__ __launch_bounds__(256) void prep_T(
    const float* __restrict__ Wn10, const float* __restrict__ Wn12,
    const float* __restrict__ Wr10, const float* __restrict__ Wr12,
    const float* __restrict__ Wout, float* __restrict__ T) {
  int i = blockIdx.x * 256 + threadIdx.x;
  if (i >= 3 * 1280) return;
  int mat = i / 1280, r = i % 1280, n = r / 10, o = r % 10;
  float s = 0.f;
  if (mat == 0) { for (int m = 0; m < 128; ++m) s += Wn10[n * 128 + m] * Wout[m * 10 + o]; }
  else if (mat == 1) { for (int m = 0; m < 128; ++m) s += Wn12[n * 128 + m] * Wout[m * 10 + o]; }
  else {
    for (int m = 0; m < 128; ++m) s += (Wr10[n * 128 + m] + Wr12[n * 128 + m]) * Wout[m * 10 + o];
    s *= 0.5f;
  }
  T[i] = s;
}

// Q1=Wn01@T1 Q2=Wr01@T1 Q3=Wn03@T2 Q4=Wr03@T2 Q5=Wn00@T3 Q6=Wn02@T3 Q7=(Wr00+Wr02)@T3
__global__ __launch_bounds__(256) void prep_Q(
    const float* __restrict__ Wn01, const float* __restrict__ Wr01,
    const float* __restrict__ Wn03, const float* __restrict__ Wr03,
    const float* __restrict__ Wn00, const float* __restrict__ Wn02,
    const float* __restrict__ Wr00, const float* __restrict__ Wr02,
    const float* __restrict__ T, float* __restrict__ Q) {
  int i = blockIdx.x * 256 + threadIdx.x;
  if (i >= 7 * 1280) return;
  int q = i / 1280, r = i % 1280, k = r / 10, o = r % 10;
  const float* T1 = T, *T2 = T + 1280, *T3 = T + 2560;
  float s = 0.f;
  switch (q) {
    case 0: for (int n = 0; n < 128; ++n) s += Wn01[k * 128 + n] * T1[n * 10 + o]; break;
    case 1: for (int n = 0; n < 128; ++n) s += Wr01[k * 128 + n] * T1[n * 10 + o]; break;
    case 2: for (int n = 0; n < 128; ++n) s += Wn03[k * 128 + n] * T2[n * 10 + o]; break;
    case 3: for (int n = 0; n < 128; ++n) s += Wr03[k * 128 + n] * T2[n * 10 + o]; break;
    case 4: for (int n = 0; n < 128; ++n) s += Wn00[k * 128 + n] * T3[n * 10 + o]; break;
    case 5: for (int n = 0; n < 128; ++n) s += Wn02[k * 128 + n] * T3[n * 10 + o]; break;
    default: for (int n = 0; n < 128; ++n) s += (Wr00[k * 128 + n] + Wr02[k * 128 + n]) * T3[n * 10 + o]; break;
  }
  Q[i] = s;
}

// Final 45x10 coefficient table B:
// rows 0..16  : B_c  (17 coeffs of F̄_c)
// rows 17..33 : B_p
// rows 34..41 : B_t  (x_t)
// row  42     : u_c (×G_c), 43: u_p (×G_p), 44: k (const)
__global__ __launch_bounds__(256) void prep_B(
    const float* __restrict__ Wcol, const float* __restrict__ bcol,
    const float* __restrict__ b_lin, const float* __restrict__ Wout,
    const float* __restrict__ bout, const float* __restrict__ T,
    const float* __restrict__ Q, float* __restrict__ B) {
  int i = blockIdx.x * 256 + threadIdx.x;
  if (i >= 450) return;
  int r = i / 10, o = i % 10;
  const float* WcC = Wcol, *WcT = Wcol + 128, *WcP = Wcol + 256;
  const float* bC = bcol, *bT = bcol + 128, *bP = bcol + 256;
  const float* Q1 = Q, *Q2 = Q + 1280, *Q3 = Q + 2560, *Q4 = Q + 3840;
  const float* Q5 = Q + 5120, *Q6 = Q + 6400, *Q7 = Q + 7680;
  const float* T1 = T, *T2 = T + 1280, *T3 = T + 2560;
  const float* b00 = b_lin, *b01 = b_lin + 128, *b02 = b_lin + 256, *b03 = b_lin + 384;
  const float* b10 = b_lin + 512, *b12 = b_lin + 768;
  float s = 0.f;
  if (r < 8) {                       // B_c[0:8] = 0.5·E_T⊙Q1 (coeff of g·x̄_t(c))
    int j = r;
    for (int d = 0; d < 16; ++d) s += WcT[j * 16 + d] * Q1[(j * 16 + d) * 10 + o];
    s *= 0.5f;
  } else if (r < 16) {               // B_c[8:16] = 0.5·E_C⊙(Q2+Q5) (x_c; merged f_t term)
    int j = r - 8;
    for (int d = 0; d < 16; ++d)
      s += WcC[j * 16 + d] * (Q2[(j * 16 + d) * 10 + o] + Q5[(j * 16 + d) * 10 + o]);
    s *= 0.5f;
  } else if (r == 16) {              // B_c[16] = 0.5·βT@Q1 (coeff of mean g(c))
    for (int k2 = 0; k2 < 128; ++k2) s += bT[k2] * Q1[k2 * 10 + o];
    s *= 0.5f;
  } else if (r < 25) {               // B_p[0:8]
    int j = r - 17;
    for (int d = 0; d < 16; ++d) s += WcT[j * 16 + d] * Q3[(j * 16 + d) * 10 + o];
    s *= 0.5f;
  } else if (r < 33) {               // B_p[8:16]
    int j = r - 25;
    for (int d = 0; d < 16; ++d)
      s += WcP[j * 16 + d] * (Q4[(j * 16 + d) * 10 + o] + Q6[(j * 16 + d) * 10 + o]);
    s *= 0.5f;
  } else if (r == 33) {              // B_p[16]
    for (int k2 = 0; k2 < 128; ++k2) s += bT[k2] * Q3[k2 * 10 + o];
    s *= 0.5f;
  } else if (r < 42) {               // B_t = 0.5·E_T⊙Q7 (x_t)
    int j = r - 34;
    for (int d = 0; d < 16; ++d) s += WcT[j * 16 + d] * Q7[(j * 16 + d) * 10 + o];
    s *= 0.5f;
  } else if (r == 42) {              // u_c = 0.5·(βC@(Q2+Q5) + b01@T1)
    for (int k2 = 0; k2 < 128; ++k2) s += bC[k2] * (Q2[k2 * 10 + o] + Q5[k2 * 10 + o]);
    for (int n = 0; n < 128; ++n) s += b01[n] * T1[n * 10 + o];
    s *= 0.5f;
  } else if (r == 43) {              // u_p = 0.5·(βP@(Q4+Q6) + b03@T2)
    for (int k2 = 0; k2 < 128; ++k2) s += bP[k2] * (Q4[k2 * 10 + o] + Q6[k2 * 10 + o]);
    for (int n = 0; n < 128; ++n) s += b03[n] * T2[n * 10 + o];
    s *= 0.5f;
  } else {                           // k = 0.5·((b10+b12)@Wout + βT@Q7 + (b00+b02)@T3) + bout
    for (int n = 0; n < 128; ++n) s += (b10[n] + b12[n]) * Wout[n * 10 + o];
    for (int k2 = 0; k2 < 128; ++k2) s += bT[k2] * Q7[k2 * 10 + o];
    for (int n = 0; n < 128; ++n) s += (b00[n] + b02[n]) * T3[n * 10 + o];
    s *= 0.5f;
    s += bout[o];
  }
  B[i] = s;
}

// ---------------- one-hop z rows: z = [g·x̄_t (8), x_own (8), g, pad3] ----------------
__global__ __launch_bounds__(256) void build_z(
    const float* __restrict__ xt, const float* __restrict__ xown,
    const int* __restrict__ off, const int* __restrict__ pool,
    float* __restrict__ z, int n) {
  int c = blockIdx.x * 256 + threadIdx.x;
  if (c >= n) return;
  int j0 = off[c], j1 = off[c + 1], deg = j1 - j0;
  float s[8];
  #pragma unroll
  for (int i = 0; i < 8; ++i) s[i] = 0.f;
  for (int j = j0; j < j1; ++j) {
    int t = pool[j];
    const float4* p = (const float4*)(xt + (size_t)t * 8);
    float4 a = p[0], b = p[1];
    s[0] += a.x; s[1] += a.y; s[2] += a.z; s[3] += a.w;
    s[4] += b.x; s[5] += b.y; s[6] += b.z; s[7] += b.w;
  }
  float g = deg > 0 ? 1.f : 0.f;
  float inv = g / fmaxf((float)deg, 1.f);
  const float4* xo = (const float4*)(xown + (size_t)c * 8);
  float4* zp = (float4*)(z + (size_t)c * ZST);
  zp[0] = make_float4(s[0] * inv, s[1] * inv, s[2] * inv, s[3] * inv);
  zp[1] = make_float4(s[4] * inv, s[5] * inv, s[6] * inv, s[7] * inv);
  zp[2] = xo[0];
  zp[3] = xo[1];
  zp[4] = make_float4(g, 0.f, 0.f, 0.f);
}

// ---------------- final: per-transaction gather + 44x10 matvec + softmax ----------------
__global__ __launch_bounds__(256) void final_t(
    const float* __restrict__ xt, const float* __restrict__ zc,
    const float* __restrict__ zp, const int* __restrict__ offc,
    const int* __restrict__ offp, const int* __restrict__ pool,
    const float* __restrict__ B, float* __restrict__ out, int n) {
  __shared__ float sB[450];
  int tid = threadIdx.x;
  for (int i = tid; i < 450; i += 256) sB[i] = B[i];
  __syncthreads();
  int t = blockIdx.x * 256 + tid;
  if (t >= n) return;

  float Fc[17], Fp[17];
  #pragma unroll
  for (int i = 0; i < 17; ++i) { Fc[i] = 0.f; Fp[i] = 0.f; }

  int jc0 = offc[t], jc1 = offc[t + 1];
  int jp0 = offp[t], jp1 = offp[t + 1];
  for (int j = jc0; j < jc1; ++j) {
    const float4* p = (const float4*)(zc + (size_t)pool[j] * ZST);
    float4 a = p[0], b = p[1], c = p[2], d = p[3], e = p[4];
    Fc[0] += a.x; Fc[1] += a.y; Fc[2] += a.z; Fc[3] += a.w;
    Fc[4] += b.x; Fc[5] += b.y; Fc[6] += b.z; Fc[7] += b.w;
    Fc[8] += c.x; Fc[9] += c.y; Fc[10] += c.z; Fc[11] += c.w;
    Fc[12] += d.x; Fc[13] += d.y; Fc[14] += d.z; Fc[15] += d.w;
    Fc[16] += e.x;
  }
  for (int j = jp0; j < jp1; ++j) {
    const float4* p = (const float4*)(zp + (size_t)pool[j] * ZST);
    float4 a = p[0], b = p[1], c = p[2], d = p[3], e = p[4];
    Fp[0] += a.x; Fp[1] += a.y; Fp[2] += a.z; Fp[3] += a.w;
    Fp[4] += b.x; Fp[5] += b.y; Fp[6] += b.z; Fp[7] += b.w;
    Fp[8] += c.x; Fp[9] += c.y; Fp[10] += c.z; Fp[11] += c.w;
    Fp[12] += d.x; Fp[13] += d.y; Fp[14] += d.z; Fp[15] += d.w;
    Fp[16] += e.x;
  }
  int dc = jc1 - jc0, dp = jp1 - jp0;
  float Gc = dc > 0 ? 1.f : 0.f, Gp = dp > 0 ? 1.f : 0.f;
  float ivc = Gc / fmaxf((float)dc, 1.f), ivp = Gp / fmaxf((float)dp, 1.f);
  #pragma unroll
  for (int i = 0; i < 17; ++i) { Fc[i] *= ivc; Fp[i] *= ivp; }

  const float4* xp4 = (const float4*)(xt + (size_t)t * 8);
  float4 xa = xp4[0], xb = xp4[1];
  float xv[8] = {xa.x, xa.y, xa.z, xa.w, xb.x, xb.y, xb.z, xb.w};

  float lg[OUTC];
  #pragma unroll
  for (int o = 0; o < OUTC; ++o)
    lg[o] = sB[44 * 10 + o] + Gc * sB[42 * 10 + o] + Gp * sB[43 * 10 + o];
  #pragma unroll
  for (int r = 0; r < 17; ++r) {
    float fc = Fc[r], fp = Fp[r];
    #pragma unroll
    for (int o = 0; o < OUTC; ++o)
      lg[o] += fc * sB[r * 10 + o] + fp * sB[(17 + r) * 10 + o];
  }
  #pragma unroll
  for (int r = 0; r < 8; ++r) {
    float xr = xv[r];
    #pragma unroll
    for (int o = 0; o < OUTC; ++o) lg[o] += xr * sB[(34 + r) * 10 + o];
  }

  float m = lg[0];
  #pragma unroll
  for (int o = 1; o < OUTC; ++o) m = fmaxf(m, lg[o]);
  float s = 0.f;
  #pragma unroll
  for (int o = 0; o < OUTC; ++o) { lg[o] = __expf(lg[o] - m); s += lg[o]; }
  float invs = 1.0f / s;
  float* op = &out[(size_t)t * OUTC];
  #pragma unroll
  for (int o = 0; o < 5; ++o) {
    float2 p2; p2.x = lg[2 * o] * invs; p2.y = lg[2 * o + 1] * invs;
    *(float2*)&op[2 * o] = p2;
  }
}

extern "C" void kernel_launch(void* const* d_in, const int* in_sizes, int n_in,
                              void* d_out, int out_size, void* d_ws, size_t ws_size,
                              hipStream_t stream) {
  const float* x_c   = (const float*)d_in[0];
  const float* x_t   = (const float*)d_in[1];
  const float* x_p   = (const float*)d_in[2];
  const float* W_col = (const float*)d_in[3];
  const float* b_col = (const float*)d_in[4];
  const float* Wn    = (const float*)d_in[5];
  const float* Wr    = (const float*)d_in[6];
  const float* b_lin = (const float*)d_in[7];
  const float* W_out = (const float*)d_in[8];
  const float* b_out = (const float*)d_in[9];
  const int* e_m_src = (const int*)d_in[10];
  const int* e_m_dst = (const int*)d_in[11];
  const int* e_i_src = (const int*)d_in[12];
  const int* e_i_dst = (const int*)d_in[13];
  float* out = (float*)d_out;

  // ---- workspace carve-out (~30 MB) ----
  size_t cursor = 0;
  char* base = (char*)d_ws;
  auto alloc = [&](size_t bytes) {
    void* p = base + cursor;
    cursor += (bytes + 255) & ~(size_t)255;
    return p;
  };
  int* pool = (int*)alloc((size_t)TOTE * 4);
  int* cnt  = (int*)alloc((size_t)NTOT * 4);
  int* off  = (int*)alloc((size_t)(NTOT + 1) * 4);
  int* cur  = (int*)alloc((size_t)(NTOT + 1) * 4);
  int* bsum = (int*)alloc(1024 * 4);
  float* z_c = (float*)alloc((size_t)NCV * ZST * 4);
  float* z_p = (float*)alloc((size_t)NPV * ZST * 4);
  float* T   = (float*)alloc(3 * 1280 * 4);
  float* Q   = (float*)alloc(7 * 1280 * 4);
  float* B   = (float*)alloc(450 * 4);

  // CSR seg bases: seg0 [0,NT): t<-c (makes); seg1 [NT,2NT): t<-p (in);
  // seg2 [2NT,2NT+NC): c<-t (makes); seg3: p<-t (in).
  const int S0 = 0, S1 = NTV, S2 = 2 * NTV, S3 = 2 * NTV + NCV;

  const float* Wn_l[2][4]; const float* Wr_l[2][4];
  for (int l = 0; l < 2; ++l)
    for (int r = 0; r < 4; ++r) {
      Wn_l[l][r] = Wn + (size_t)(l * 4 + r) * DD * DD;
      Wr_l[l][r] = Wr + (size_t)(l * 4 + r) * DD * DD;
    }

  int gEM = (EMV + 255) / 256, gEI = (EIV + 255) / 256;

  // ---- weight folding (independent chain) ----
  prep_T<<<15, 256, 0, stream>>>(Wn_l[1][0], Wn_l[1][2], Wr_l[1][0], Wr_l[1][2],
                                 W_out, T);
  prep_Q<<<35, 256, 0, stream>>>(Wn_l[0][1], Wr_l[0][1], Wn_l[0][3], Wr_l[0][3],
                                 Wn_l[0][0], Wn_l[0][2], Wr_l[0][0], Wr_l[0][2],
                                 T, Q);
  prep_B<<<2, 256, 0, stream>>>(W_col, b_col, b_lin, W_out, b_out, T, Q, B);

  // ---- CSR build ----
  hipMemsetAsync(cnt, 0, (size_t)NTOT * 4, stream);
  count_kernel<<<gEM, 256, 0, stream>>>(e_m_dst, cnt + S0, EMV);
  count_kernel<<<gEI, 256, 0, stream>>>(e_i_dst, cnt + S1, EIV);
  count_kernel<<<gEM, 256, 0, stream>>>(e_m_src, cnt + S2, EMV);
  count_kernel<<<gEI, 256, 0, stream>>>(e_i_src, cnt + S3, EIV);
  int nblk = (NTOT + 1023) / 1024;  // 733
  scan1_kernel<<<nblk, 256, 0, stream>>>(cnt, off, bsum, NTOT);
  scan2_kernel<<<1, 256, 0, stream>>>(bsum, nblk);
  scan3_kernel<<<(NTOT + 1 + 255) / 256, 256, 0, stream>>>(off, bsum, cur, NTOT, TOTE);
  fill_kernel<<<gEM, 256, 0, stream>>>(e_m_dst, e_m_src, cur + S0, pool, EMV);
  fill_kernel<<<gEI, 256, 0, stream>>>(e_i_dst, e_i_src, cur + S1, pool, EIV);
  fill_kernel<<<gEM, 256, 0, stream>>>(e_m_src, e_m_dst, cur + S2, pool, EMV);
  fill_kernel<<<gEI, 256, 0, stream>>>(e_i_src, e_i_dst, cur + S3, pool, EIV);

  // ---- one-hop z rows ----
  build_z<<<(NCV + 255) / 256, 256, 0, stream>>>(x_t, x_c, off + S2, pool, z_c, NCV);
  build_z<<<(NPV + 255) / 256, 256, 0, stream>>>(x_t, x_p, off + S3, pool, z_p, NPV);

  // ---- final fused two-hop gather + matvec + softmax ----
  final_t<<<(NTV + 255) / 256, 256, 0, stream>>>(x_t, z_c, z_p, off + S0, off + S1,
                                                 pool, B, out, NTV);
}

// Round 14
// 374.417 us; speedup vs baseline: 3.3025x; 1.0588x over previous
//
#include <hip/hip_runtime.h>

#define NCV 100000
#define NTV 300000
#define NPV 50000
#define DD 128
#define OUTC 10
#define EMV 300000
#define EIV 600000
#define NTOT (2 * NTV + NCV + NPV)      // 750000 concatenated count slots
#define TOTE (2 * (EMV + EIV))          // 1800000 pool entries
#define ZST 20                           // z row stride (floats), 80B aligned

// CSR seg bases: seg0 [0,NT): t<-c (makes); seg1 [NT,2NT): t<-p (in);
// seg2 [2NT,2NT+NC): c<-t (makes); seg3: p<-t (in).
#define S0 0
#define S1 NTV
#define S2 (2 * NTV)
#define S3 (2 * NTV + NCV)

// ---------------- CSR build (fused) ----------------
__global__ __launch_bounds__(256) void count_all(
    const int* __restrict__ ems, const int* __restrict__ emd,
    const int* __restrict__ eis, const int* __restrict__ eid,
    int* __restrict__ cnt) {
  int e = blockIdx.x * 256 + threadIdx.x;
  if (e < EMV) {
    atomicAdd(&cnt[S0 + emd[e]], 1);
    atomicAdd(&cnt[S2 + ems[e]], 1);
  }
  if (e < EIV) {
    atomicAdd(&cnt[S1 + eid[e]], 1);
    atomicAdd(&cnt[S3 + eis[e]], 1);
  }
}

__global__ __launch_bounds__(256) void scan1_kernel(
    const int* __restrict__ cnt, int* __restrict__ off,
    int* __restrict__ bsum, int n) {
  __shared__ int sd[256];
  int tid = threadIdx.x;
  int base = blockIdx.x * 1024 + tid * 4;
  int v0 = 0, v1 = 0, v2 = 0, v3 = 0;
  if (base + 0 < n) v0 = cnt[base + 0];
  if (base + 1 < n) v1 = cnt[base + 1];
  if (base + 2 < n) v2 = cnt[base + 2];
  if (base + 3 < n) v3 = cnt[base + 3];
  int tsum = v0 + v1 + v2 + v3;
  sd[tid] = tsum;
  __syncthreads();
  for (int o = 1; o < 256; o <<= 1) {
    int xv = 0;
    if (tid >= o) xv = sd[tid - o];
    __syncthreads();
    sd[tid] += xv;
    __syncthreads();
  }
  int ex = sd[tid] - tsum;
  if (base + 0 < n) off[base + 0] = ex;
  if (base + 1 < n) off[base + 1] = ex + v0;
  if (base + 2 < n) off[base + 2] = ex + v0 + v1;
  if (base + 3 < n) off[base + 3] = ex + v0 + v1 + v2;
  if (tid == 255) bsum[blockIdx.x] = sd[255];
}

__global__ __launch_bounds__(256) void scan2_kernel(int* __restrict__ bsum, int nb) {
  __shared__ int sd[256];
  int tid = threadIdx.x;
  int base = tid * 4;
  int v0 = 0, v1 = 0, v2 = 0, v3 = 0;
  if (base + 0 < nb) v0 = bsum[base + 0];
  if (base + 1 < nb) v1 = bsum[base + 1];
  if (base + 2 < nb) v2 = bsum[base + 2];
  if (base + 3 < nb) v3 = bsum[base + 3];
  int tsum = v0 + v1 + v2 + v3;
  sd[tid] = tsum;
  __syncthreads();
  for (int o = 1; o < 256; o <<= 1) {
    int xv = 0;
    if (tid >= o) xv = sd[tid - o];
    __syncthreads();
    sd[tid] += xv;
    __syncthreads();
  }
  int ex = sd[tid] - tsum;
  if (base + 0 < nb) bsum[base + 0] = ex;
  if (base + 1 < nb) bsum[base + 1] = ex + v0;
  if (base + 2 < nb) bsum[base + 2] = ex + v0 + v1;
  if (base + 3 < nb) bsum[base + 3] = ex + v0 + v1 + v2;
}

__global__ __launch_bounds__(256) void scan3_kernel(
    int* __restrict__ off, const int* __restrict__ bsum,
    int* __restrict__ cur, int n, int tote) {
  int i = blockIdx.x * 256 + threadIdx.x;
  if (i > n) return;
  int v = (i == n) ? tote : (off[i] + bsum[i >> 10]);
  off[i] = v;
  cur[i] = v;
}

__global__ __launch_bounds__(256) void fill_all(
    const int* __restrict__ ems, const int* __restrict__ emd,
    const int* __restrict__ eis, const int* __restrict__ eid,
    int* __restrict__ cur, int* __restrict__ pool) {
  int e = blockIdx.x * 256 + threadIdx.x;
  if (e < EMV) {
    int p0 = atomicAdd(&cur[S0 + emd[e]], 1); pool[p0] = ems[e];
    int p2 = atomicAdd(&cur[S2 + ems[e]], 1); pool[p2] = emd[e];
  }
  if (e < EIV) {
    int p1 = atomicAdd(&cur[S1 + eid[e]], 1); pool[p1] = eis[e];
    int p3 = atomicAdd(&cur[S3 + eis[e]], 1); pool[p3] = eid[e];
  }
}

// ---------------- weight folding (wave-per-output, shuffle reduce) ----------------
// T1 = Wn10@Wout, T2 = Wn12@Wout, T3 = 0.5*(Wr10+Wr12)@Wout  (each 128x10)
__global__ __launch_bounds__(256) void prep_T_w(
    const float* __restrict__ Wn10, const float* __restrict__ Wn12,
    const float* __restrict__ Wr10, const float* __restrict__ Wr12,
    const float* __restrict__ Wout, float* __restrict__ T) {
  int gw = (blockIdx.x * 256 + threadIdx.x) >> 6;
  int lane = threadIdx.x & 63;
  if (gw >= 3 * 1280) return;
  int mat = gw / 1280, r = gw % 1280, n = r / 10, o = r % 10;
  float s = 0.f;
  #pragma unroll
  for (int mi = 0; mi < 2; ++mi) {
    int m = lane + mi * 64;
    float w;
    if (mat == 0) w = Wn10[n * 128 + m];
    else if (mat == 1) w = Wn12[n * 128 + m];
    else w = 0.5f * (Wr10[n * 128 + m] + Wr12[n * 128 + m]);
    s += w * Wout[m * 10 + o];
  }
  #pragma unroll
  for (int d = 32; d; d >>= 1) s += __shfl_xor(s, d);
  if (lane == 0) T[gw] = s;
}

// Q1=Wn01@T1 Q2=Wr01@T1 Q3=Wn03@T2 Q4=Wr03@T2 Q5=Wn00@T3 Q6=Wn02@T3 Q7=(Wr00+Wr02)@T3
__global__ __launch_bounds__(256) void prep_Q_w(
    const float* __restrict__ Wn01, const float* __restrict__ Wr01,
    const float* __restrict__ Wn03, const float* __restrict__ Wr03,
    const float* __restrict__ Wn00, const float* __restrict__ Wn02,
    const float* __restrict__ Wr00, const float* __restrict__ Wr02,
    const float* __restrict__ T, float* __restrict__ Q) {
  int gw = (blockIdx.x * 256 + threadIdx.x) >> 6;
  int lane = threadIdx.x & 63;
  if (gw >= 7 * 1280) return;
  int q = gw / 1280, r = gw % 1280, k = r / 10, o = r % 10;
  const float* T1 = T, *T2 = T + 1280, *T3 = T + 2560;
  float s = 0.f;
  #pragma unroll
  for (int ni = 0; ni < 2; ++ni) {
    int n = lane + ni * 64;
    float w, t;
    switch (q) {
      case 0: w = Wn01[k * 128 + n]; t = T1[n * 10 + o]; break;
      case 1: w = Wr01[k * 128 + n]; t = T1[n * 10 + o]; break;
      case 2: w = Wn03[k * 128 + n]; t = T2[n * 10 + o]; break;
      case 3: w = Wr03[k * 128 + n]; t = T2[n * 10 + o]; break;
      case 4: w = Wn00[k * 128 + n]; t = T3[n * 10 + o]; break;
      case 5: w = Wn02[k * 128 + n]; t = T3[n * 10 + o]; break;
      default: w = Wr00[k * 128 + n] + Wr02[k * 128 + n]; t = T3[n * 10 + o]; break;
    }
    s += w * t;
  }
  #pragma unroll
  for (int d = 32; d; d >>= 1) s += __shfl_xor(s, d);
  if (lane == 0) Q[gw] = s;
}

// Final 45x10 coefficient table B (rows: 0..16 B_c | 17..33 B_p | 34..41 B_t |
// 42 u_c | 43 u_p | 44 k). Uniform outer 0.5; bout added to row 44.
__global__ __launch_bounds__(256) void prep_B_w(
    const float* __restrict__ Wcol, const float* __restrict__ bcol,
    const float* __restrict__ b_lin, const float* __restrict__ Wout,
    const float* __restrict__ bout, const float* __restrict__ T,
    const float* __restrict__ Q, float* __restrict__ B) {
  int gw = (blockIdx.x * 256 + threadIdx.x) >> 6;
  int lane = threadIdx.x & 63;
  if (gw >= 450) return;
  int r = gw / 10, o = gw % 10;
  const float* WcC = Wcol, *WcT = Wcol + 128, *WcP = Wcol + 256;
  const float* bC = bcol, *bT = bcol + 128, *bP = bcol + 256;
  const float* Q1 = Q, *Q2 = Q + 1280, *Q3 = Q + 2560, *Q4 = Q + 3840;
  const float* Q5 = Q + 5120, *Q6 = Q + 6400, *Q7 = Q + 7680;
  const float* T1 = T, *T2 = T + 1280, *T3 = T + 2560;
  const float* b00 = b_lin, *b01 = b_lin + 128, *b02 = b_lin + 256, *b03 = b_lin + 384;
  const float* b10 = b_lin + 512, *b12 = b_lin + 768;
  float s = 0.f;
  if (r < 8) {
    if (lane < 16) s = WcT[r * 16 + lane] * Q1[(r * 16 + lane) * 10 + o];
  } else if (r < 16) {
    int j = r - 8;
    if (lane < 16)
      s = WcC[j * 16 + lane] * (Q2[(j * 16 + lane) * 10 + o] + Q5[(j * 16 + lane) * 10 + o]);
  } else if (r == 16) {
    for (int k2 = lane; k2 < 128; k2 += 64) s += bT[k2] * Q1[k2 * 10 + o];
  } else if (r < 25) {
    int j = r - 17;
    if (lane < 16) s = WcT[j * 16 + lane] * Q3[(j * 16 + lane) * 10 + o];
  } else if (r < 33) {
    int j = r - 25;
    if (lane < 16)
      s = WcP[j * 16 + lane] * (Q4[(j * 16 + lane) * 10 + o] + Q6[(j * 16 + lane) * 10 + o]);
  } else if (r == 33) {
    for (int k2 = lane; k2 < 128; k2 += 64) s += bT[k2] * Q3[k2 * 10 + o];
  } else if (r < 42) {
    int j = r - 34;
    if (lane < 16) s = WcT[j * 16 + lane] * Q7[(j * 16 + lane) * 10 + o];
  } else if (r == 42) {
    for (int k2 = lane; k2 < 128; k2 += 64)
      s += bC[k2] * (Q2[k2 * 10 + o] + Q5[k2 * 10 + o]) + b01[k2] * T1[k2 * 10 + o];
  } else if (r == 43) {
    for (int k2 = lane; k2 < 128; k2 += 64)
      s += bP[k2] * (Q4[k2 * 10 + o] + Q6[k2 * 10 + o]) + b03[k2] * T2[k2 * 10 + o];
  } else {
    for (int n = lane; n < 128; n += 64)
      s += (b10[n] + b12[n]) * Wout[n * 10 + o] + bT[n] * Q7[n * 10 + o] +
           (b00[n] + b02[n]) * T3[n * 10 + o];
  }
  #pragma unroll
  for (int d = 32; d; d >>= 1) s += __shfl_xor(s, d);
  if (lane == 0) {
    float v = s * 0.5f;
    if (r == 44) v += bout[o];
    B[gw] = v;
  }
}

// ---------------- one-hop z rows: z = [g·x̄_t (8), x_own (8), g, pad3] ----------------
__device__ __forceinline__ void z_row(
    const float* __restrict__ xt, const float* __restrict__ xo8,
    const int* __restrict__ off, const int* __restrict__ pool,
    float* __restrict__ zrow, int idx) {
  int j0 = off[idx], j1 = off[idx + 1], deg = j1 - j0;
  float s[8];
  #pragma unroll
  for (int i = 0; i < 8; ++i) s[i] = 0.f;
  for (int j = j0; j < j1; ++j) {
    int t = pool[j];
    const float4* p = (const float4*)(xt + (size_t)t * 8);
    float4 a = p[0], b = p[1];
    s[0] += a.x; s[1] += a.y; s[2] += a.z; s[3] += a.w;
    s[4] += b.x; s[5] += b.y; s[6] += b.z; s[7] += b.w;
  }
  float g = deg > 0 ? 1.f : 0.f;
  float inv = g / fmaxf((float)deg, 1.f);
  const float4* xo = (const float4*)xo8;
  float4* zp = (float4*)zrow;
  zp[0] = make_float4(s[0] * inv, s[1] * inv, s[2] * inv, s[3] * inv);
  zp[1] = make_float4(s[4] * inv, s[5] * inv, s[6] * inv, s[7] * inv);
  zp[2] = xo[0];
  zp[3] = xo[1];
  zp[4] = make_float4(g, 0.f, 0.f, 0.f);
}

__global__ __launch_bounds__(256) void build_z_all(
    const float* __restrict__ xt, const float* __restrict__ xc,
    const float* __restrict__ xp, const int* __restrict__ offC,
    const int* __restrict__ offP, const int* __restrict__ pool,
    float* __restrict__ zc, float* __restrict__ zp) {
  int i = blockIdx.x * 256 + threadIdx.x;
  if (i < NCV) {
    z_row(xt, xc + (size_t)i * 8, offC, pool, zc + (size_t)i * ZST, i);
  } else if (i < NCV + NPV) {
    int p = i - NCV;
    z_row(xt, xp + (size_t)p * 8, offP, pool, zp + (size_t)p * ZST, p);
  }
}

// ---------------- final: per-transaction gather + 44x10 matvec + softmax ----------------
__global__ __launch_bounds__(256) void final_t(
    const float* __restrict__ xt, const float* __restrict__ zc,
    const float* __restrict__ zp, const int* __restrict__ offc,
    const int* __restrict__ offp, const int* __restrict__ pool,
    const float* __restrict__ B, float* __restrict__ out, int n) {
  __shared__ float sB[450];
  int tid = threadIdx.x;
  for (int i = tid; i < 450; i += 256) sB[i] = B[i];
  __syncthreads();
  int t = blockIdx.x * 256 + tid;
  if (t >= n) return;

  float Fc[17], Fp[17];
  #pragma unroll
  for (int i = 0; i < 17; ++i) { Fc[i] = 0.f; Fp[i] = 0.f; }

  int jc0 = offc[t], jc1 = offc[t + 1];
  int jp0 = offp[t], jp1 = offp[t + 1];
  for (int j = jc0; j < jc1; ++j) {
    const float4* p = (const float4*)(zc + (size_t)pool[j] * ZST);
    float4 a = p[0], b = p[1], c = p[2], d = p[3], e = p[4];
    Fc[0] += a.x; Fc[1] += a.y; Fc[2] += a.z; Fc[3] += a.w;
    Fc[4] += b.x; Fc[5] += b.y; Fc[6] += b.z; Fc[7] += b.w;
    Fc[8] += c.x; Fc[9] += c.y; Fc[10] += c.z; Fc[11] += c.w;
    Fc[12] += d.x; Fc[13] += d.y; Fc[14] += d.z; Fc[15] += d.w;
    Fc[16] += e.x;
  }
  for (int j = jp0; j < jp1; ++j) {
    const float4* p = (const float4*)(zp + (size_t)pool[j] * ZST);
    float4 a = p[0], b = p[1], c = p[2], d = p[3], e = p[4];
    Fp[0] += a.x; Fp[1] += a.y; Fp[2] += a.z; Fp[3] += a.w;
    Fp[4] += b.x; Fp[5] += b.y; Fp[6] += b.z; Fp[7] += b.w;
    Fp[8] += c.x; Fp[9] += c.y; Fp[10] += c.z; Fp[11] += c.w;
    Fp[12] += d.x; Fp[13] += d.y; Fp[14] += d.z; Fp[15] += d.w;
    Fp[16] += e.x;
  }
  int dc = jc1 - jc0, dp = jp1 - jp0;
  float Gc = dc > 0 ? 1.f : 0.f, Gp = dp > 0 ? 1.f : 0.f;
  float ivc = Gc / fmaxf((float)dc, 1.f), ivp = Gp / fmaxf((float)dp, 1.f);
  #pragma unroll
  for (int i = 0; i < 17; ++i) { Fc[i] *= ivc; Fp[i] *= ivp; }

  const float4* xp4 = (const float4*)(xt + (size_t)t * 8);
  float4 xa = xp4[0], xb = xp4[1];
  float xv[8] = {xa.x, xa.y, xa.z, xa.w, xb.x, xb.y, xb.z, xb.w};

  float lg[OUTC];
  #pragma unroll
  for (int o = 0; o < OUTC; ++o)
    lg[o] = sB[44 * 10 + o] + Gc * sB[42 * 10 + o] + Gp * sB[43 * 10 + o];
  #pragma unroll
  for (int r = 0; r < 17; ++r) {
    float fc = Fc[r], fp = Fp[r];
    #pragma unroll
    for (int o = 0; o < OUTC; ++o)
      lg[o] += fc * sB[r * 10 + o] + fp * sB[(17 + r) * 10 + o];
  }
  #pragma unroll
  for (int r = 0; r < 8; ++r) {
    float xr = xv[r];
    #pragma unroll
    for (int o = 0; o < OUTC; ++o) lg[o] += xr * sB[(34 + r) * 10 + o];
  }

  float m = lg[0];
  #pragma unroll
  for (int o = 1; o < OUTC; ++o) m = fmaxf(m, lg[o]);
  float s = 0.f;
  #pragma unroll
  for (int o = 0; o < OUTC; ++o) { lg[o] = __expf(lg[o] - m); s += lg[o]; }
  float invs = 1.0f / s;
  float* op = &out[(size_t)t * OUTC];
  #pragma unroll
  for (int o = 0; o < 5; ++o) {
    float2 p2; p2.x = lg[2 * o] * invs; p2.y = lg[2 * o + 1] * invs;
    *(float2*)&op[2 * o] = p2;
  }
}

extern "C" void kernel_launch(void* const* d_in, const int* in_sizes, int n_in,
                              void* d_out, int out_size, void* d_ws, size_t ws_size,
                              hipStream_t stream) {
  const float* x_c   = (const float*)d_in[0];
  const float* x_t   = (const float*)d_in[1];
  const float* x_p   = (const float*)d_in[2];
  const float* W_col = (const float*)d_in[3];
  const float* b_col = (const float*)d_in[4];
  const float* Wn    = (const float*)d_in[5];
  const float* Wr    = (const float*)d_in[6];
  const float* b_lin = (const float*)d_in[7];
  const float* W_out = (const float*)d_in[8];
  const float* b_out = (const float*)d_in[9];
  const int* e_m_src = (const int*)d_in[10];
  const int* e_m_dst = (const int*)d_in[11];
  const int* e_i_src = (const int*)d_in[12];
  const int* e_i_dst = (const int*)d_in[13];
  float* out = (float*)d_out;

  // ---- workspace carve-out (~30 MB; ws_size = 256 MiB) ----
  size_t cursor = 0;
  char* base = (char*)d_ws;
  auto alloc = [&](size_t bytes) {
    void* p = base + cursor;
    cursor += (bytes + 255) & ~(size_t)255;
    return p;
  };
  int* pool = (int*)alloc((size_t)TOTE * 4);
  int* cnt  = (int*)alloc((size_t)NTOT * 4);
  int* off  = (int*)alloc((size_t)(NTOT + 1) * 4);
  int* cur  = (int*)alloc((size_t)(NTOT + 1) * 4);
  int* bsum = (int*)alloc(1024 * 4);
  float* z_c = (float*)alloc((size_t)NCV * ZST * 4);
  float* z_p = (float*)alloc((size_t)NPV * ZST * 4);
  float* T   = (float*)alloc(3 * 1280 * 4);
  float* Q   = (float*)alloc(7 * 1280 * 4);
  float* B   = (float*)alloc(450 * 4);

  const float* Wn_l[2][4]; const float* Wr_l[2][4];
  for (int l = 0; l < 2; ++l)
    for (int r = 0; r < 4; ++r) {
      Wn_l[l][r] = Wn + (size_t)(l * 4 + r) * DD * DD;
      Wr_l[l][r] = Wr + (size_t)(l * 4 + r) * DD * DD;
    }

  int gEI = (EIV + 255) / 256;

  // ---- weight folding (wave-per-output; dependent chain but each ~2 µs) ----
  prep_T_w<<<(3 * 1280 * 64 + 255) / 256, 256, 0, stream>>>(
      Wn_l[1][0], Wn_l[1][2], Wr_l[1][0], Wr_l[1][2], W_out, T);
  prep_Q_w<<<(7 * 1280 * 64 + 255) / 256, 256, 0, stream>>>(
      Wn_l[0][1], Wr_l[0][1], Wn_l[0][3], Wr_l[0][3],
      Wn_l[0][0], Wn_l[0][2], Wr_l[0][0], Wr_l[0][2], T, Q);
  prep_B_w<<<(450 * 64 + 255) / 256, 256, 0, stream>>>(
      W_col, b_col, b_lin, W_out, b_out, T, Q, B);

  // ---- CSR build (fused dispatches) ----
  hipMemsetAsync(cnt, 0, (size_t)NTOT * 4, stream);
  count_all<<<gEI, 256, 0, stream>>>(e_m_src, e_m_dst, e_i_src, e_i_dst, cnt);
  int nblk = (NTOT + 1023) / 1024;  // 733
  scan1_kernel<<<nblk, 256, 0, stream>>>(cnt, off, bsum, NTOT);
  scan2_kernel<<<1, 256, 0, stream>>>(bsum, nblk);
  scan3_kernel<<<(NTOT + 1 + 255) / 256, 256, 0, stream>>>(off, bsum, cur, NTOT, TOTE);
  fill_all<<<gEI, 256, 0, stream>>>(e_m_src, e_m_dst, e_i_src, e_i_dst, cur, pool);

  // ---- one-hop z rows (c and p fused) ----
  build_z_all<<<(NCV + NPV + 255) / 256, 256, 0, stream>>>(
      x_t, x_c, x_p, off + S2, off + S3, pool, z_c, z_p);

  // ---- final fused two-hop gather + matvec + softmax ----
  final_t<<<(NTV + 255) / 256, 256, 0, stream>>>(x_t, z_c, z_p, off + S0, off + S1,
                                                 pool, B, out, NTV);
}

// Round 15
// 335.084 us; speedup vs baseline: 3.6901x; 1.1174x over previous
//
#include <hip/hip_runtime.h>

#define NCV 100000
#define NTV 300000
#define NPV 50000
#define DD 128
#define OUTC 10
#define EMV 300000
#define EIV 600000
#define CST 12   // acc_c / acc_p / y row stride (floats)
#define TST 24   // acc_t row stride (floats): [yc(10), dc, pad, yp(10), dp, pad]

// ---------------- weight folding (wave-per-output, shuffle reduce) ----------------
// T1 = Wn10@Wout, T2 = Wn12@Wout, T3 = 0.5*(Wr10+Wr12)@Wout  (each 128x10)
__global__ __launch_bounds__(256) void prep_T_w(
    const float* __restrict__ Wn10, const float* __restrict__ Wn12,
    const float* __restrict__ Wr10, const float* __restrict__ Wr12,
    const float* __restrict__ Wout, float* __restrict__ T) {
  int gw = (blockIdx.x * 256 + threadIdx.x) >> 6;
  int lane = threadIdx.x & 63;
  if (gw >= 3 * 1280) return;
  int mat = gw / 1280, r = gw % 1280, n = r / 10, o = r % 10;
  float s = 0.f;
  #pragma unroll
  for (int mi = 0; mi < 2; ++mi) {
    int m = lane + mi * 64;
    float w;
    if (mat == 0) w = Wn10[n * 128 + m];
    else if (mat == 1) w = Wn12[n * 128 + m];
    else w = 0.5f * (Wr10[n * 128 + m] + Wr12[n * 128 + m]);
    s += w * Wout[m * 10 + o];
  }
  #pragma unroll
  for (int d = 32; d; d >>= 1) s += __shfl_xor(s, d);
  if (lane == 0) T[gw] = s;
}

// Q1=Wn01@T1 Q2=Wr01@T1 Q3=Wn03@T2 Q4=Wr03@T2 Q5=Wn00@T3 Q6=Wn02@T3 Q7=(Wr00+Wr02)@T3
__global__ __launch_bounds__(256) void prep_Q_w(
    const float* __restrict__ Wn01, const float* __restrict__ Wr01,
    const float* __restrict__ Wn03, const float* __restrict__ Wr03,
    const float* __restrict__ Wn00, const float* __restrict__ Wn02,
    const float* __restrict__ Wr00, const float* __restrict__ Wr02,
    const float* __restrict__ T, float* __restrict__ Q) {
  int gw = (blockIdx.x * 256 + threadIdx.x) >> 6;
  int lane = threadIdx.x & 63;
  if (gw >= 7 * 1280) return;
  int q = gw / 1280, r = gw % 1280, k = r / 10, o = r % 10;
  const float* T1 = T, *T2 = T + 1280, *T3 = T + 2560;
  float s = 0.f;
  #pragma unroll
  for (int ni = 0; ni < 2; ++ni) {
    int n = lane + ni * 64;
    float w, t;
    switch (q) {
      case 0: w = Wn01[k * 128 + n]; t = T1[n * 10 + o]; break;
      case 1: w = Wr01[k * 128 + n]; t = T1[n * 10 + o]; break;
      case 2: w = Wn03[k * 128 + n]; t = T2[n * 10 + o]; break;
      case 3: w = Wr03[k * 128 + n]; t = T2[n * 10 + o]; break;
      case 4: w = Wn00[k * 128 + n]; t = T3[n * 10 + o]; break;
      case 5: w = Wn02[k * 128 + n]; t = T3[n * 10 + o]; break;
      default: w = Wr00[k * 128 + n] + Wr02[k * 128 + n]; t = T3[n * 10 + o]; break;
    }
    s += w * t;
  }
  #pragma unroll
  for (int d = 32; d; d >>= 1) s += __shfl_xor(s, d);
  if (lane == 0) Q[gw] = s;
}

// Final 45x10 coefficient table B (rows: 0..16 B_c | 17..33 B_p | 34..41 B_t |
// 42 u_c | 43 u_p | 44 k). Uniform outer 0.5; bout added to row 44.
__global__ __launch_bounds__(256) void prep_B_w(
    const float* __restrict__ Wcol, const float* __restrict__ bcol,
    const float* __restrict__ b_lin, const float* __restrict__ Wout,
    const float* __restrict__ bout, const float* __restrict__ T,
    const float* __restrict__ Q, float* __restrict__ B) {
  int gw = (blockIdx.x * 256 + threadIdx.x) >> 6;
  int lane = threadIdx.x & 63;
  if (gw >= 450) return;
  int r = gw / 10, o = gw % 10;
  const float* WcC = Wcol, *WcT = Wcol + 128, *WcP = Wcol + 256;
  const float* bC = bcol, *bT = bcol + 128, *bP = bcol + 256;
  const float* Q1 = Q, *Q2 = Q + 1280, *Q3 = Q + 2560, *Q4 = Q + 3840;
  const float* Q5 = Q + 5120, *Q6 = Q + 6400, *Q7 = Q + 7680;
  const float* T1 = T, *T2 = T + 1280, *T3 = T + 2560;
  const float* b00 = b_lin, *b01 = b_lin + 128, *b02 = b_lin + 256, *b03 = b_lin + 384;
  const float* b10 = b_lin + 512, *b12 = b_lin + 768;
  float s = 0.f;
  if (r < 8) {
    if (lane < 16) s = WcT[r * 16 + lane] * Q1[(r * 16 + lane) * 10 + o];
  } else if (r < 16) {
    int j = r - 8;
    if (lane < 16)
      s = WcC[j * 16 + lane] * (Q2[(j * 16 + lane) * 10 + o] + Q5[(j * 16 + lane) * 10 + o]);
  } else if (r == 16) {
    for (int k2 = lane; k2 < 128; k2 += 64) s += bT[k2] * Q1[k2 * 10 + o];
  } else if (r < 25) {
    int j = r - 17;
    if (lane < 16) s = WcT[j * 16 + lane] * Q3[(j * 16 + lane) * 10 + o];
  } else if (r < 33) {
    int j = r - 25;
    if (lane < 16)
      s = WcP[j * 16 + lane] * (Q4[(j * 16 + lane) * 10 + o] + Q6[(j * 16 + lane) * 10 + o]);
  } else if (r == 33) {
    for (int k2 = lane; k2 < 128; k2 += 64) s += bT[k2] * Q3[k2 * 10 + o];
  } else if (r < 42) {
    int j = r - 34;
    if (lane < 16) s = WcT[j * 16 + lane] * Q7[(j * 16 + lane) * 10 + o];
  } else if (r == 42) {
    for (int k2 = lane; k2 < 128; k2 += 64)
      s += bC[k2] * (Q2[k2 * 10 + o] + Q5[k2 * 10 + o]) + b01[k2] * T1[k2 * 10 + o];
  } else if (r == 43) {
    for (int k2 = lane; k2 < 128; k2 += 64)
      s += bP[k2] * (Q4[k2 * 10 + o] + Q6[k2 * 10 + o]) + b03[k2] * T2[k2 * 10 + o];
  } else {
    for (int n = lane; n < 128; n += 64)
      s += (b10[n] + b12[n]) * Wout[n * 10 + o] + bT[n] * Q7[n * 10 + o] +
           (b00[n] + b02[n]) * T3[n * 10 + o];
  }
  #pragma unroll
  for (int d = 32; d; d >>= 1) s += __shfl_xor(s, d);
  if (lane == 0) {
    float v = s * 0.5f;
    if (r == 44) v += bout[o];
    B[gw] = v;
  }
}

// ---------------- Pass A: edge-parallel scatter of x_t into acc_c / acc_p ----------------
// 8 lanes per edge; lane j adds x_t[t][j]; lane 0 also counts.
__global__ __launch_bounds__(256) void passA(
    const float* __restrict__ xt,
    const int* __restrict__ ems, const int* __restrict__ emd,
    const int* __restrict__ eis, const int* __restrict__ eid,
    float* __restrict__ acc_c, float* __restrict__ acc_p) {
  int gid = blockIdx.x * 256 + threadIdx.x;
  int e = gid >> 3, j = gid & 7;
  if (e < EMV) {
    int c = ems[e], t = emd[e];
    unsafeAtomicAdd(&acc_c[(size_t)c * CST + j], xt[(size_t)t * 8 + j]);
    if (j == 0) unsafeAtomicAdd(&acc_c[(size_t)c * CST + 8], 1.0f);
  }
  if (e < EIV) {
    int p = eis[e], t = eid[e];
    unsafeAtomicAdd(&acc_p[(size_t)p * CST + j], xt[(size_t)t * 8 + j]);
    if (j == 0) unsafeAtomicAdd(&acc_p[(size_t)p * CST + 8], 1.0f);
  }
}

// ---------------- finalize: z = [g·x̄_t, x_own, g]  ->  y = z @ B_side (10 floats) ----------------
__global__ __launch_bounds__(256) void finalize_y(
    const float* __restrict__ acc_c, const float* __restrict__ acc_p,
    const float* __restrict__ xc, const float* __restrict__ xp,
    const float* __restrict__ B, float* __restrict__ y_c, float* __restrict__ y_p) {
  int i = blockIdx.x * 256 + threadIdx.x;
  if (i >= NCV + NPV) return;
  bool isC = i < NCV;
  int idx = isC ? i : i - NCV;
  const float* acc = (isC ? acc_c : acc_p) + (size_t)idx * CST;
  const float* xo = (isC ? xc : xp) + (size_t)idx * 8;
  const float* Bs = B + (isC ? 0 : 17 * 10);
  float* y = (isC ? y_c : y_p) + (size_t)idx * CST;

  float cntv = acc[8];
  float g = cntv > 0.f ? 1.f : 0.f;
  float inv = g / fmaxf(cntv, 1.f);
  float lg[OUTC];
  #pragma unroll
  for (int o = 0; o < OUTC; ++o) lg[o] = g * Bs[16 * 10 + o];
  #pragma unroll
  for (int r = 0; r < 8; ++r) {
    float zb = acc[r] * inv;   // g·x̄_t component
    float zo = xo[r];          // own-x component
    #pragma unroll
    for (int o = 0; o < OUTC; ++o)
      lg[o] += zb * Bs[r * 10 + o] + zo * Bs[(8 + r) * 10 + o];
  }
  #pragma unroll
  for (int o = 0; o < OUTC; ++o) y[o] = lg[o];
  y[10] = 0.f; y[11] = 0.f;
}

// ---------------- Pass B: edge-parallel scatter of y into acc_t ----------------
// 16 lanes per edge; lanes 0..9 add y, lane 10 counts.
__global__ __launch_bounds__(256) void passB(
    const float* __restrict__ y_c, const float* __restrict__ y_p,
    const int* __restrict__ ems, const int* __restrict__ emd,
    const int* __restrict__ eis, const int* __restrict__ eid,
    float* __restrict__ acc_t) {
  int gid = blockIdx.x * 256 + threadIdx.x;
  int e = gid >> 4, j = gid & 15;
  if (e < EMV) {
    int c = ems[e], t = emd[e];
    if (j < 10) unsafeAtomicAdd(&acc_t[(size_t)t * TST + j], y_c[(size_t)c * CST + j]);
    else if (j == 10) unsafeAtomicAdd(&acc_t[(size_t)t * TST + 10], 1.0f);
  }
  if (e < EIV) {
    int p = eis[e], t = eid[e];
    if (j < 10) unsafeAtomicAdd(&acc_t[(size_t)t * TST + 12 + j], y_p[(size_t)p * CST + j]);
    else if (j == 10) unsafeAtomicAdd(&acc_t[(size_t)t * TST + 22], 1.0f);
  }
}

// ---------------- final: coalesced per-t combine + softmax ----------------
__global__ __launch_bounds__(256) void final_t(
    const float* __restrict__ acc_t, const float* __restrict__ xt,
    const float* __restrict__ B, float* __restrict__ out, int n) {
  __shared__ float sB[450];
  int tid = threadIdx.x;
  for (int i = tid; i < 450; i += 256) sB[i] = B[i];
  __syncthreads();
  int t = blockIdx.x * 256 + tid;
  if (t >= n) return;

  const float* row = acc_t + (size_t)t * TST;
  float dc = row[10], dp = row[22];
  float Gc = dc > 0.f ? 1.f : 0.f, Gp = dp > 0.f ? 1.f : 0.f;
  float ivc = 1.f / fmaxf(dc, 1.f), ivp = 1.f / fmaxf(dp, 1.f);

  const float4* xp4 = (const float4*)(xt + (size_t)t * 8);
  float4 xa = xp4[0], xb = xp4[1];
  float xv[8] = {xa.x, xa.y, xa.z, xa.w, xb.x, xb.y, xb.z, xb.w};

  float lg[OUTC];
  #pragma unroll
  for (int o = 0; o < OUTC; ++o)
    lg[o] = row[o] * ivc + row[12 + o] * ivp +
            Gc * sB[42 * 10 + o] + Gp * sB[43 * 10 + o] + sB[44 * 10 + o];
  #pragma unroll
  for (int r = 0; r < 8; ++r) {
    float xr = xv[r];
    #pragma unroll
    for (int o = 0; o < OUTC; ++o) lg[o] += xr * sB[(34 + r) * 10 + o];
  }

  float m = lg[0];
  #pragma unroll
  for (int o = 1; o < OUTC; ++o) m = fmaxf(m, lg[o]);
  float s = 0.f;
  #pragma unroll
  for (int o = 0; o < OUTC; ++o) { lg[o] = __expf(lg[o] - m); s += lg[o]; }
  float invs = 1.0f / s;
  float* op = &out[(size_t)t * OUTC];
  #pragma unroll
  for (int o = 0; o < 5; ++o) {
    float2 p2; p2.x = lg[2 * o] * invs; p2.y = lg[2 * o + 1] * invs;
    *(float2*)&op[2 * o] = p2;
  }
}

extern "C" void kernel_launch(void* const* d_in, const int* in_sizes, int n_in,
                              void* d_out, int out_size, void* d_ws, size_t ws_size,
                              hipStream_t stream) {
  const float* x_c   = (const float*)d_in[0];
  const float* x_t   = (const float*)d_in[1];
  const float* x_p   = (const float*)d_in[2];
  const float* W_col = (const float*)d_in[3];
  const float* b_col = (const float*)d_in[4];
  const float* Wn    = (const float*)d_in[5];
  const float* Wr    = (const float*)d_in[6];
  const float* b_lin = (const float*)d_in[7];
  const float* W_out = (const float*)d_in[8];
  const float* b_out = (const float*)d_in[9];
  const int* e_m_src = (const int*)d_in[10];
  const int* e_m_dst = (const int*)d_in[11];
  const int* e_i_src = (const int*)d_in[12];
  const int* e_i_dst = (const int*)d_in[13];
  float* out = (float*)d_out;

  // ---- workspace carve-out (~44 MB; ws_size = 256 MiB) ----
  size_t cursor = 0;
  char* base = (char*)d_ws;
  auto alloc = [&](size_t bytes) {
    void* p = base + cursor;
    cursor += (bytes + 255) & ~(size_t)255;
    return p;
  };
  float* acc_c = (float*)alloc((size_t)NCV * CST * 4);  // 4.8 MB
  float* acc_p = (float*)alloc((size_t)NPV * CST * 4);  // 2.4 MB
  float* acc_t = (float*)alloc((size_t)NTV * TST * 4);  // 28.8 MB
  float* y_c   = (float*)alloc((size_t)NCV * CST * 4);  // 4.8 MB
  float* y_p   = (float*)alloc((size_t)NPV * CST * 4);  // 2.4 MB
  float* T     = (float*)alloc(3 * 1280 * 4);
  float* Q     = (float*)alloc(7 * 1280 * 4);
  float* B     = (float*)alloc(450 * 4);

  const float* Wn_l[2][4]; const float* Wr_l[2][4];
  for (int l = 0; l < 2; ++l)
    for (int r = 0; r < 4; ++r) {
      Wn_l[l][r] = Wn + (size_t)(l * 4 + r) * DD * DD;
      Wr_l[l][r] = Wr + (size_t)(l * 4 + r) * DD * DD;
    }

  // ---- zero accumulators (contiguous: acc_c|acc_p|acc_t, all 256-aligned sizes) ----
  hipMemsetAsync(acc_c, 0, ((size_t)NCV * CST + (size_t)NPV * CST + (size_t)NTV * TST) * 4,
                 stream);

  // ---- weight folding ----
  prep_T_w<<<(3 * 1280 * 64 + 255) / 256, 256, 0, stream>>>(
      Wn_l[1][0], Wn_l[1][2], Wr_l[1][0], Wr_l[1][2], W_out, T);
  prep_Q_w<<<(7 * 1280 * 64 + 255) / 256, 256, 0, stream>>>(
      Wn_l[0][1], Wr_l[0][1], Wn_l[0][3], Wr_l[0][3],
      Wn_l[0][0], Wn_l[0][2], Wr_l[0][0], Wr_l[0][2], T, Q);
  prep_B_w<<<(450 * 64 + 255) / 256, 256, 0, stream>>>(
      W_col, b_col, b_lin, W_out, b_out, T, Q, B);

  // ---- Pass A: scatter x_t into acc_c / acc_p ----
  passA<<<(EIV * 8 + 255) / 256, 256, 0, stream>>>(
      x_t, e_m_src, e_m_dst, e_i_src, e_i_dst, acc_c, acc_p);

  // ---- finalize y rows (projection through B) ----
  finalize_y<<<(NCV + NPV + 255) / 256, 256, 0, stream>>>(
      acc_c, acc_p, x_c, x_p, B, y_c, y_p);

  // ---- Pass B: scatter y into acc_t ----
  passB<<<(EIV * 16 + 255) / 256, 256, 0, stream>>>(
      y_c, y_p, e_m_src, e_m_dst, e_i_src, e_i_dst, acc_t);

  // ---- final combine + softmax ----
  final_t<<<(NTV + 255) / 256, 256, 0, stream>>>(acc_t, x_t, B, out, NTV);
}